// Round 15
// baseline (271.467 us; speedup 1.0000x reference)
//
#include <hip/hip_runtime.h>
#include <math.h>

#define BB 4
#define CC 64
#define HH 128
#define WW 128
#define HWP 16384

typedef _Float16 h2 __attribute__((ext_vector_type(2)));
typedef _Float16 h4 __attribute__((ext_vector_type(4)));
typedef __fp16  p2 __attribute__((ext_vector_type(2)));   // cvt_pkrtz's return type
typedef float f32x4 __attribute__((ext_vector_type(4)));
union HU { unsigned u; h2 h; p2 p; };
union U2H { uint2 u; h4 h; };
static __device__ __forceinline__ h2 u2h(unsigned x){ HU v; v.u = x; return v.h; }
static __device__ __forceinline__ unsigned pk2u(float a, float b){
    HU v; v.p = __builtin_amdgcn_cvt_pkrtz(a, b); return v.u;
}

// ---------------- kT: build f13t[b][y][x][64 pairs u32] (f16 channel pairs).
// pairs 0..31 = f1 channels (2cp,2cp+1); pairs 32..63 = f3 channels.
__global__ __launch_bounds__(256) void kT(
    const float* __restrict__ f1, const float* __restrict__ f3,
    unsigned* __restrict__ f13t)
{
    __shared__ float lt[64*129];
    int b = blockIdx.x >> 7, y = blockIdx.x & 127;
    int t = threadIdx.x;
    unsigned* dst = f13t + ((size_t)((b << 14) + (y << 7)))*64;
    for (int half = 0; half < 2; ++half) {
        const float* src = (half == 0 ? f1 : f3) + (((size_t)b*64) << 14) + (y << 7);
#pragma unroll 4
        for (int i = 0; i < 32; ++i) {
            int idx = i*256 + t; int c = idx >> 7, x = idx & 127;
            lt[c*129 + x] = src[(c << 14) + x];
        }
        __syncthreads();
#pragma unroll 4
        for (int i = 0; i < 16; ++i) {
            int idx = i*256 + t; int x = idx >> 5, cp = idx & 31;
            dst[x*64 + half*32 + cp] = pk2u(lt[(2*cp)*129 + x], lt[(2*cp+1)*129 + x]);
        }
        __syncthreads();
    }
}

// ---------------- K0: pack weights into MFMA A-fragments; zero stats.
// wmf (k2): u32 idx ((r*64+l)*36+kb)*2+j; P = kb*8+(l>>4)*2+j, kt = P>>5,
//   cp = P&31 (f1 pairs); out-ch r*16+(l&15).
// wof (k1): u32 idx ((mt*64+l)*72+kb)*2+j; P = kb*8+(l>>4)*2+j in [0,576);
//   kt = P>>6, cp = P&63 (concat pair); och = mt*16+(l&15), zero if och>=27.
__global__ __launch_bounds__(256) void k0_wt(
    const float* __restrict__ ow, const float* __restrict__ mw,
    unsigned* __restrict__ wmf, unsigned* __restrict__ wof,
    float* __restrict__ stats)
{
    if (blockIdx.x == 0 && threadIdx.x < 128) stats[threadIdx.x] = 0.f;
    int i = blockIdx.x*256 + threadIdx.x;
    if (i < 18432) {                           // wmf: 4*64*36*2
        int j   = i & 1;
        int t2  = i >> 1;
        int kb  = t2 % 36;
        int rl  = t2 / 36;
        int l   = rl & 63;
        int r   = rl >> 6;
        int row = l & 15, ksel = l >> 4;
        int och = r*16 + row;
        int P   = kb*8 + ksel*2 + j;           // 0..287
        int kt  = P >> 5;
        int cp  = P & 31;
        float lo = mw[och*576 + (2*cp    )*9 + kt];
        float hi = mw[och*576 + (2*cp + 1)*9 + kt];
        wmf[i] = pk2u(lo, hi);
    } else if (i < 36864) {                    // wof: 2*64*72*2
        int idx = i - 18432;
        int j   = idx & 1;
        int t2  = idx >> 1;
        int kb  = t2 % 72;
        int rl  = t2 / 72;
        int l   = rl & 63;
        int mt  = rl >> 6;
        int row = l & 15, ksel = l >> 4;
        int och = mt*16 + row;
        int P   = kb*8 + ksel*2 + j;           // 0..575
        int kt  = P >> 6;                      // tap 0..8
        int cp  = P & 63;                      // concat pair
        unsigned v = 0;
        if (och < 27) {
            float lo = ow[(och*128 + 2*cp    )*9 + kt];
            float hi = ow[(och*128 + 2*cp + 1)*9 + kt];
            v = pk2u(lo, hi);
        }
        wof[idx] = v;
    }
}

// ---------------- K1: offset conv via MFMA. block = quarter-row (32 px),
// 4 waves = 2 M-tiles x 2 px-tiles; K = 576 pairs in 3 tap-row chunks.
__global__ __launch_bounds__(256) void k1_offset_conv(
    const unsigned* __restrict__ f13t, const unsigned* __restrict__ wof,
    const float* __restrict__ ob, float* __restrict__ om)
{
    __shared__ unsigned tile[34*68];

    int blk = blockIdx.x;        // b(2) y(7) xq(2)
    int xq = blk & 3;
    int y  = (blk >> 2) & 127;
    int b  = blk >> 9;

    int tid  = threadIdx.x;
    int lane = tid & 63;
    int wv   = tid >> 6;
    int mt   = wv >> 1;          // M-tile (out-ch 16*mt..)
    int pxt  = wv & 1;           // px-tile
    int row  = lane & 15;
    int ksel = lane >> 4;

    f32x4 acc = {0.f, 0.f, 0.f, 0.f};
    const unsigned* wbase = wof + (size_t)(mt*64 + lane)*144;

#pragma unroll 1
    for (int dy = 0; dy < 3; ++dy) {
        int yy = y + dy - 1;
        bool yok = (unsigned)yy < (unsigned)HH;
        __syncthreads();
        for (int i = tid; i < 544; i += 256) {
            int px34 = i >> 4, q = i & 15;
            int gxp = xq*32 - 1 + px34;
            uint4 v = make_uint4(0u, 0u, 0u, 0u);
            if (yok && (unsigned)gxp < (unsigned)WW)
                v = *(const uint4*)&f13t[(((size_t)(b*128 + yy))*128 + gxp)*64 + q*4];
            *(uint4*)&tile[px34*68 + q*4] = v;
        }
        __syncthreads();

#pragma unroll
        for (int hf = 0; hf < 2; ++hf) {
            uint4 wq[6];
#pragma unroll
            for (int m = 0; m < 6; ++m)
                wq[m] = *(const uint4*)&wbase[dy*48 + hf*24 + m*4];
#pragma unroll
            for (int kl = 0; kl < 12; ++kl) {
                int Pl  = (hf*12 + kl)*8 + ksel*2;
                int ktl = Pl >> 6;
                int cp  = Pl & 63;
                U2H wa;
                uint4 q = wq[kl >> 1];
                if (kl & 1) { wa.u.x = q.z; wa.u.y = q.w; }
                else        { wa.u.x = q.x; wa.u.y = q.y; }
                U2H bfr;
                bfr.u = *(const uint2*)&tile[(pxt*16 + row + ktl)*68 + cp];
                acc = __builtin_amdgcn_mfma_f32_16x16x16f16(wa.h, bfr.h, acc, 0, 0, 0);
            }
        }
    }

    int gx = xq*32 + pxt*16 + row;
#pragma unroll
    for (int rI = 0; rI < 4; ++rI) {
        int och = mt*16 + ksel*4 + rI;
        if (och < 27) {
            float v = acc[rI] + ob[och];
            if (och >= 18) v = 1.f / (1.f + __expf(-v));   // mask sigmoid
            om[((b*27 + och) << 14) + (y << 7) + gx] = v;
        }
    }
}

// ---------------- K2: deformable conv (R13 body: f32 phase A, 16-lane groups,
// uint2 taps) + fused per-channel stats epilogue.
// block = quarter-row (32 px), 4 waves; grid 2048.
// LDS: params 864 + sl[32][100] = 16,256 B.
__global__ __launch_bounds__(256) void k2_deform(
    const unsigned* __restrict__ f13t, const unsigned* __restrict__ wmf,
    const float* __restrict__ om, float* __restrict__ aligned,
    float* __restrict__ stats)
{
    extern __shared__ unsigned lds[];
    unsigned* pl_a = lds;            // [9][32] addr|dx<<14|dy<<15
    unsigned* pl_w = lds + 288;      // [9][32] x uint2 {half2(w00,w01), half2(w10,w11)}
    unsigned* sl   = lds + 864;      // [32 px][100] half2 samples (one third)

    int blk = blockIdx.x;        // b(2) y(7) xq(2)
    int xq = blk & 3;
    int y  = (blk >> 2) & 127;
    int b  = blk >> 9;

    int tid  = threadIdx.x;
    int lane = tid & 63;
    int wv   = tid >> 6;
    int row  = lane & 15;
    int ksel = lane >> 4;
    int chg  = lane & 15;        // phase-A channel group (4 ch = 2 pairs)
    int ig   = lane >> 4;        // phase-A item subgroup 0..3

    const float* omb = om + ((b*27) << 14) + (y << 7);
    const unsigned* ftb = f13t + (((size_t)b) << 20);

    // ---- param pre-phase: 288 items (k, px)
    for (int i = tid; i < 288; i += 256) {
        int k = i >> 5, lpx = i & 31;
        int gxp = xq*32 + lpx;
        float off0 = omb[((2*k)   << 14) + gxp];
        float off1 = omb[((2*k+1) << 14) + gxp];
        float mk   = omb[((18+k)  << 14) + gxp];   // sigmoided in K1

        float pyf = (float)y   + (float)(k/3) - 1.f + off0;
        float pxg = (float)gxp + (float)(k%3) - 1.f + off1;
        float fy = floorf(pyf), fx = floorf(pxg);
        int y0 = (int)fy, x0 = (int)fx;
        float wy = pyf - fy, wx = pxg - fx;
        float oy = 1.f - wy, ox = 1.f - wx;
        bool yv0 = (unsigned)y0     < (unsigned)HH;
        bool yv1 = (unsigned)(y0+1) < (unsigned)HH;
        bool xv0 = (unsigned)x0     < (unsigned)WW;
        bool xv1 = (unsigned)(x0+1) < (unsigned)WW;
        int y0c = min(max(y0, 0), 127);
        int x0c = min(max(x0, 0), 127);
        int dy = min(max(y0+1, 0), 127) - y0c;   // 0 or 1
        int dx = min(max(x0+1, 0), 127) - x0c;   // 0 or 1
        unsigned a = (unsigned)((y0c << 7) + x0c) | ((unsigned)dx << 14) | ((unsigned)dy << 15);
        float w00 = (yv0 && xv0) ? oy*ox*mk : 0.f;
        float w01 = (yv0 && xv1) ? oy*wx*mk : 0.f;
        float w10 = (yv1 && xv0) ? wy*ox*mk : 0.f;
        float w11 = (yv1 && xv1) ? wy*wx*mk : 0.f;
        pl_a[i] = a;
        pl_w[i*2]     = pk2u(w00, w01);
        pl_w[i*2 + 1] = pk2u(w10, w11);
    }
    __syncthreads();

    f32x4 acc0 = {0.f, 0.f, 0.f, 0.f};
    f32x4 acc1 = {0.f, 0.f, 0.f, 0.f};

    const unsigned* wbase = wmf + (wv*64 + lane)*72;

#pragma unroll 1
    for (int th = 0; th < 3; ++th) {
        uint4 wq[6];
#pragma unroll
        for (int m = 0; m < 6; ++m)
            wq[m] = *(const uint4*)&wbase[th*24 + m*4];

        // phase A: 96 items (ktl,px); lane group of 16 = one item
#pragma unroll 2
        for (int it = 0; it < 6; ++it) {
            int item = (it*4 + wv)*4 + ig;     // 0..95
            int ktl  = item >> 5;              // 0..2
            int px   = item & 31;
            int k    = th*3 + ktl;
            int pidx = k*32 + px;
            unsigned a = pl_a[pidx];
            uint2 wpk = *(const uint2*)&pl_w[pidx*2];
            int i00 = (int)(a & 0x3FFFu);
            int dx  = (int)((a >> 14) & 1u);
            int i10 = i00 + (((int)(a >> 15) & 1) << 7);
            h2 hw01 = u2h(wpk.x);
            h2 hw23 = u2h(wpk.y);
            float w00 = (float)hw01.x, w01 = (float)hw01.y;
            float w10 = (float)hw23.x, w11 = (float)hw23.y;

            uint2 r00 = *(const uint2*)&ftb[(size_t)(i00     )*64 + 2*chg];
            uint2 r01 = *(const uint2*)&ftb[(size_t)(i00 + dx)*64 + 2*chg];
            uint2 r10 = *(const uint2*)&ftb[(size_t)(i10     )*64 + 2*chg];
            uint2 r11 = *(const uint2*)&ftb[(size_t)(i10 + dx)*64 + 2*chg];

            h2 a00 = u2h(r00.x), b00 = u2h(r00.y);
            h2 a01 = u2h(r01.x), b01 = u2h(r01.y);
            h2 a10 = u2h(r10.x), b10 = u2h(r10.y);
            h2 a11 = u2h(r11.x), b11 = u2h(r11.y);

            float v0 = w00*(float)a00.x + w01*(float)a01.x + w10*(float)a10.x + w11*(float)a11.x;
            float v1 = w00*(float)a00.y + w01*(float)a01.y + w10*(float)a10.y + w11*(float)a11.y;
            float v2 = w00*(float)b00.x + w01*(float)b01.x + w10*(float)b10.x + w11*(float)b11.x;
            float v3 = w00*(float)b00.y + w01*(float)b01.y + w10*(float)b10.y + w11*(float)b11.y;

            uint2 pkd;
            pkd.x = pk2u(v0, v1);
            pkd.y = pk2u(v2, v3);
            *(uint2*)&sl[px*100 + ktl*32 + 2*chg] = pkd;
        }
        __syncthreads();

        // phase B: 12 kb16 x 2 px-tiles MFMA
        const unsigned* b0p = &sl[(row     )*100 + ksel*2];
        const unsigned* b1p = &sl[(16+row  )*100 + ksel*2];
#pragma unroll
        for (int kbl = 0; kbl < 12; ++kbl) {
            U2H wa;
            uint4 q = wq[kbl >> 1];
            if (kbl & 1) { wa.u.x = q.z; wa.u.y = q.w; }
            else         { wa.u.x = q.x; wa.u.y = q.y; }
            U2H b0, b1;
            b0.u = *(const uint2*)&b0p[kbl*8];
            b1.u = *(const uint2*)&b1p[kbl*8];
            acc0 = __builtin_amdgcn_mfma_f32_16x16x16f16(wa.h, b0.h, acc0, 0, 0, 0);
            acc1 = __builtin_amdgcn_mfma_f32_16x16x16f16(wa.h, b1.h, acc1, 0, 0, 0);
        }
        __syncthreads();
    }

    // write aligned + fused per-channel stats (sum, sumsq over this block's 32 px)
    int obase = ((b*CC) << 14) + (y << 7) + xq*32;
#pragma unroll
    for (int rI = 0; rI < 4; ++rI) {
        int och = wv*16 + ksel*4 + rI;
        float v0 = acc0[rI], v1 = acc1[rI];
        aligned[obase + (och << 14) + row]      = v0;
        aligned[obase + (och << 14) + 16 + row] = v1;
        float s  = v0 + v1;
        float sq = v0*v0 + v1*v1;
#pragma unroll
        for (int off = 1; off < 16; off <<= 1) {
            s  += __shfl_xor(s,  off, 64);
            sq += __shfl_xor(sq, off, 64);
        }
        if (row == 0) {
            atomicAdd(&stats[och],      s);
            atomicAdd(&stats[64 + och], sq);
        }
    }
}

// ---------------- K4: in-place normalize + affine (stats from k2 atomics)
__global__ __launch_bounds__(256) void k4_norm(
    float* __restrict__ a, const float* __restrict__ stats,
    const float* __restrict__ gamma, const float* __restrict__ beta)
{
    const float invN = 1.f / 65536.f;
    int n4 = (BB*CC*HWP) / 4;
    for (int i4 = blockIdx.x*256 + threadIdx.x; i4 < n4; i4 += gridDim.x*256) {
        int c = (i4 >> 12) & 63;
        float mean = stats[c] * invN;
        float var  = stats[64 + c] * invN - mean*mean;
        float sc = gamma[c] * rsqrtf(var + 1e-5f);
        float sh = beta[c] - mean*sc;
        float4 v = ((const float4*)a)[i4];
        v.x = v.x*sc + sh; v.y = v.y*sc + sh;
        v.z = v.z*sc + sh; v.w = v.w*sc + sh;
        ((float4*)a)[i4] = v;
    }
}

extern "C" void kernel_launch(void* const* d_in, const int* in_sizes, int n_in,
                              void* d_out, int out_size, void* d_ws, size_t ws_size,
                              hipStream_t stream)
{
    const float* f1    = (const float*)d_in[0];
    const float* f3    = (const float*)d_in[1];
    const float* ow    = (const float*)d_in[2];
    const float* ob    = (const float*)d_in[3];
    const float* mw    = (const float*)d_in[4];
    const float* gamma = (const float*)d_in[5];
    const float* beta  = (const float*)d_in[6];
    float* out = (float*)d_out;

    float* om     = (float*)d_ws;                 // [4][27][128][128] = 7,077,888 B
    float* stats  = om + 4*27*HWP;                // [128] floats
    unsigned* wmf = (unsigned*)(stats + 512);     // 18432 u32
    unsigned* wof = wmf + 18432;                  // 18432 u32
    unsigned* f13t = wof + 18432;                 // [4][128][128][64] u32 = 16 MB

    const int lds2 = (864 + 32*100) * 4;          // 16,256 B
    (void)hipFuncSetAttribute((const void*)k2_deform,
        hipFuncAttributeMaxDynamicSharedMemorySize, lds2);

    hipLaunchKernelGGL(k0_wt, dim3(144), dim3(256), 0, stream, ow, mw, wmf, wof, stats);
    hipLaunchKernelGGL(kT, dim3(512), dim3(256), 0, stream, f1, f3, f13t);
    hipLaunchKernelGGL(k1_offset_conv, dim3(2048), dim3(256), 0, stream,
                       f13t, wof, ob, om);
    hipLaunchKernelGGL(k2_deform, dim3(2048), dim3(256), lds2, stream,
                       f13t, wmf, om, out, stats);
    hipLaunchKernelGGL(k4_norm, dim3(2048), dim3(256), 0, stream,
                       out, stats, gamma, beta);
}

// Round 16
// 98.456 us; speedup vs baseline: 2.7572x; 2.7572x over previous
//
#include <hip/hip_runtime.h>
#include <math.h>

#define BB 4
#define CC 64
#define HH 128
#define WW 128
#define HWP 16384

typedef _Float16 h2 __attribute__((ext_vector_type(2)));
typedef _Float16 h4 __attribute__((ext_vector_type(4)));
typedef __fp16  p2 __attribute__((ext_vector_type(2)));   // cvt_pkrtz's return type
typedef float f32x4 __attribute__((ext_vector_type(4)));
union HU { unsigned u; h2 h; p2 p; };
union U2H { uint2 u; h4 h; };
static __device__ __forceinline__ h2 u2h(unsigned x){ HU v; v.u = x; return v.h; }
static __device__ __forceinline__ unsigned pk2u(float a, float b){
    HU v; v.p = __builtin_amdgcn_cvt_pkrtz(a, b); return v.u;
}

// ---------------- kT: build f13t[b][y][x][64 pairs u32] (f16 channel pairs).
// pairs 0..31 = f1 channels (2cp,2cp+1); pairs 32..63 = f3 channels.
__global__ __launch_bounds__(256) void kT(
    const float* __restrict__ f1, const float* __restrict__ f3,
    unsigned* __restrict__ f13t)
{
    __shared__ float lt[64*129];
    int b = blockIdx.x >> 7, y = blockIdx.x & 127;
    int t = threadIdx.x;
    unsigned* dst = f13t + ((size_t)((b << 14) + (y << 7)))*64;
    for (int half = 0; half < 2; ++half) {
        const float* src = (half == 0 ? f1 : f3) + (((size_t)b*64) << 14) + (y << 7);
#pragma unroll 4
        for (int i = 0; i < 32; ++i) {
            int idx = i*256 + t; int c = idx >> 7, x = idx & 127;
            lt[c*129 + x] = src[(c << 14) + x];
        }
        __syncthreads();
#pragma unroll 4
        for (int i = 0; i < 16; ++i) {
            int idx = i*256 + t; int x = idx >> 5, cp = idx & 31;
            dst[x*64 + half*32 + cp] = pk2u(lt[(2*cp)*129 + x], lt[(2*cp+1)*129 + x]);
        }
        __syncthreads();
    }
}

// ---------------- K0: pack weights into MFMA A-fragments.
// wmf (k2): u32 idx ((r*64+l)*36+kb)*2+j; P = kb*8+(l>>4)*2+j, kt = P>>5,
//   cp = P&31 (f1 pairs); out-ch r*16+(l&15).
// wof (k1): u32 idx ((mt*64+l)*72+kb)*2+j; P = kb*8+(l>>4)*2+j in [0,576);
//   kt = P>>6, cp = P&63 (concat pair); och = mt*16+(l&15), zero if och>=27.
__global__ __launch_bounds__(256) void k0_wt(
    const float* __restrict__ ow, const float* __restrict__ mw,
    unsigned* __restrict__ wmf, unsigned* __restrict__ wof)
{
    int i = blockIdx.x*256 + threadIdx.x;
    if (i < 18432) {                           // wmf: 4*64*36*2
        int j   = i & 1;
        int t2  = i >> 1;
        int kb  = t2 % 36;
        int rl  = t2 / 36;
        int l   = rl & 63;
        int r   = rl >> 6;
        int row = l & 15, ksel = l >> 4;
        int och = r*16 + row;
        int P   = kb*8 + ksel*2 + j;           // 0..287
        int kt  = P >> 5;
        int cp  = P & 31;
        float lo = mw[och*576 + (2*cp    )*9 + kt];
        float hi = mw[och*576 + (2*cp + 1)*9 + kt];
        wmf[i] = pk2u(lo, hi);
    } else if (i < 36864) {                    // wof: 2*64*72*2
        int idx = i - 18432;
        int j   = idx & 1;
        int t2  = idx >> 1;
        int kb  = t2 % 72;
        int rl  = t2 / 72;
        int l   = rl & 63;
        int mt  = rl >> 6;
        int row = l & 15, ksel = l >> 4;
        int och = mt*16 + row;
        int P   = kb*8 + ksel*2 + j;           // 0..575
        int kt  = P >> 6;                      // tap 0..8
        int cp  = P & 63;                      // concat pair
        unsigned v = 0;
        if (och < 27) {
            float lo = ow[(och*128 + 2*cp    )*9 + kt];
            float hi = ow[(och*128 + 2*cp + 1)*9 + kt];
            v = pk2u(lo, hi);
        }
        wof[idx] = v;
    }
}

// ---------------- K1: offset conv via MFMA. block = quarter-row (32 px),
// 4 waves = 2 M-tiles x 2 px-tiles; K = 576 pairs in 3 tap-row chunks.
__global__ __launch_bounds__(256) void k1_offset_conv(
    const unsigned* __restrict__ f13t, const unsigned* __restrict__ wof,
    const float* __restrict__ ob, float* __restrict__ om)
{
    __shared__ unsigned tile[34*68];

    int blk = blockIdx.x;        // b(2) y(7) xq(2)
    int xq = blk & 3;
    int y  = (blk >> 2) & 127;
    int b  = blk >> 9;

    int tid  = threadIdx.x;
    int lane = tid & 63;
    int wv   = tid >> 6;
    int mt   = wv >> 1;          // M-tile (out-ch 16*mt..)
    int pxt  = wv & 1;           // px-tile
    int row  = lane & 15;
    int ksel = lane >> 4;

    f32x4 acc = {0.f, 0.f, 0.f, 0.f};
    const unsigned* wbase = wof + (size_t)(mt*64 + lane)*144;

#pragma unroll 1
    for (int dy = 0; dy < 3; ++dy) {
        int yy = y + dy - 1;
        bool yok = (unsigned)yy < (unsigned)HH;
        __syncthreads();
        for (int i = tid; i < 544; i += 256) {
            int px34 = i >> 4, q = i & 15;
            int gxp = xq*32 - 1 + px34;
            uint4 v = make_uint4(0u, 0u, 0u, 0u);
            if (yok && (unsigned)gxp < (unsigned)WW)
                v = *(const uint4*)&f13t[(((size_t)(b*128 + yy))*128 + gxp)*64 + q*4];
            *(uint4*)&tile[px34*68 + q*4] = v;
        }
        __syncthreads();

#pragma unroll
        for (int hf = 0; hf < 2; ++hf) {
            uint4 wq[6];
#pragma unroll
            for (int m = 0; m < 6; ++m)
                wq[m] = *(const uint4*)&wbase[dy*48 + hf*24 + m*4];
#pragma unroll
            for (int kl = 0; kl < 12; ++kl) {
                int Pl  = (hf*12 + kl)*8 + ksel*2;
                int ktl = Pl >> 6;
                int cp  = Pl & 63;
                U2H wa;
                uint4 q = wq[kl >> 1];
                if (kl & 1) { wa.u.x = q.z; wa.u.y = q.w; }
                else        { wa.u.x = q.x; wa.u.y = q.y; }
                U2H bfr;
                bfr.u = *(const uint2*)&tile[(pxt*16 + row + ktl)*68 + cp];
                acc = __builtin_amdgcn_mfma_f32_16x16x16f16(wa.h, bfr.h, acc, 0, 0, 0);
            }
        }
    }

    int gx = xq*32 + pxt*16 + row;
#pragma unroll
    for (int rI = 0; rI < 4; ++rI) {
        int och = mt*16 + ksel*4 + rI;
        if (och < 27) {
            float v = acc[rI] + ob[och];
            if (och >= 18) v = 1.f / (1.f + __expf(-v));   // mask sigmoid
            om[((b*27 + och) << 14) + (y << 7) + gx] = v;
        }
    }
}

// ---------------- K2: deformable conv. R13 phase A (f32, 16-lane groups,
// uint2 taps) + Q-permuted sl + ds_read_b128 phase B (layout verified R14).
// sl layout: pair P stored at sigma(P) = (P>>4)*16 + ((P>>1)&3)*4
//   + ((P>>3)&1)*2 + (P&1); the two u32s of a writer stay adjacent, so the
//   writer is a lane-constant index remap (swz). NO atomics (R15 lesson:
//   262K contended atomicAdds to 128 floats cost ~180 us).
// LDS: params 864 + sl[32][100] = 16,256 B.
__global__ __launch_bounds__(256) void k2_deform(
    const unsigned* __restrict__ f13t, const unsigned* __restrict__ wmf,
    const float* __restrict__ om, float* __restrict__ aligned)
{
    extern __shared__ unsigned lds[];
    unsigned* pl_a = lds;            // [9][32] addr|dx<<14|dy<<15
    unsigned* pl_w = lds + 288;      // [9][32] x uint2 {half2(w00,w01), half2(w10,w11)}
    unsigned* sl   = lds + 864;      // [32 px][100] permuted half2 samples

    int blk = blockIdx.x;        // b(2) y(7) xq(2)
    int xq = blk & 3;
    int y  = (blk >> 2) & 127;
    int b  = blk >> 9;

    int tid  = threadIdx.x;
    int lane = tid & 63;
    int wv   = tid >> 6;
    int row  = lane & 15;
    int ksel = lane >> 4;
    int chg  = lane & 15;        // phase-A channel group (4 ch = 2 pairs)
    int ig   = lane >> 4;        // phase-A item subgroup 0..3
    // lane-constant permuted write column for pairs (2chg, 2chg+1):
    int swz  = ((chg >> 3) << 4) | ((chg & 3) << 2) | (((chg >> 2) & 1) << 1);

    const float* omb = om + ((b*27) << 14) + (y << 7);
    const unsigned* ftb = f13t + (((size_t)b) << 20);

    // ---- param pre-phase: 288 items (k, px)
    for (int i = tid; i < 288; i += 256) {
        int k = i >> 5, lpx = i & 31;
        int gxp = xq*32 + lpx;
        float off0 = omb[((2*k)   << 14) + gxp];
        float off1 = omb[((2*k+1) << 14) + gxp];
        float mk   = omb[((18+k)  << 14) + gxp];   // sigmoided in K1

        float pyf = (float)y   + (float)(k/3) - 1.f + off0;
        float pxg = (float)gxp + (float)(k%3) - 1.f + off1;
        float fy = floorf(pyf), fx = floorf(pxg);
        int y0 = (int)fy, x0 = (int)fx;
        float wy = pyf - fy, wx = pxg - fx;
        float oy = 1.f - wy, ox = 1.f - wx;
        bool yv0 = (unsigned)y0     < (unsigned)HH;
        bool yv1 = (unsigned)(y0+1) < (unsigned)HH;
        bool xv0 = (unsigned)x0     < (unsigned)WW;
        bool xv1 = (unsigned)(x0+1) < (unsigned)WW;
        int y0c = min(max(y0, 0), 127);
        int x0c = min(max(x0, 0), 127);
        int dy = min(max(y0+1, 0), 127) - y0c;   // 0 or 1
        int dx = min(max(x0+1, 0), 127) - x0c;   // 0 or 1
        unsigned a = (unsigned)((y0c << 7) + x0c) | ((unsigned)dx << 14) | ((unsigned)dy << 15);
        float w00 = (yv0 && xv0) ? oy*ox*mk : 0.f;
        float w01 = (yv0 && xv1) ? oy*wx*mk : 0.f;
        float w10 = (yv1 && xv0) ? wy*ox*mk : 0.f;
        float w11 = (yv1 && xv1) ? wy*wx*mk : 0.f;
        pl_a[i] = a;
        pl_w[i*2]     = pk2u(w00, w01);
        pl_w[i*2 + 1] = pk2u(w10, w11);
    }
    __syncthreads();

    f32x4 acc0 = {0.f, 0.f, 0.f, 0.f};
    f32x4 acc1 = {0.f, 0.f, 0.f, 0.f};

    const unsigned* wbase = wmf + (wv*64 + lane)*72;

#pragma unroll 1
    for (int th = 0; th < 3; ++th) {
        uint4 wq[6];
#pragma unroll
        for (int m = 0; m < 6; ++m)
            wq[m] = *(const uint4*)&wbase[th*24 + m*4];

        // phase A: 96 items (ktl,px); lane group of 16 = one item
#pragma unroll 2
        for (int it = 0; it < 6; ++it) {
            int item = (it*4 + wv)*4 + ig;     // 0..95
            int ktl  = item >> 5;              // 0..2
            int px   = item & 31;
            int k    = th*3 + ktl;
            int pidx = k*32 + px;
            unsigned a = pl_a[pidx];
            uint2 wpk = *(const uint2*)&pl_w[pidx*2];
            int i00 = (int)(a & 0x3FFFu);
            int dx  = (int)((a >> 14) & 1u);
            int i10 = i00 + (((int)(a >> 15) & 1) << 7);
            h2 hw01 = u2h(wpk.x);
            h2 hw23 = u2h(wpk.y);
            float w00 = (float)hw01.x, w01 = (float)hw01.y;
            float w10 = (float)hw23.x, w11 = (float)hw23.y;

            uint2 r00 = *(const uint2*)&ftb[(size_t)(i00     )*64 + 2*chg];
            uint2 r01 = *(const uint2*)&ftb[(size_t)(i00 + dx)*64 + 2*chg];
            uint2 r10 = *(const uint2*)&ftb[(size_t)(i10     )*64 + 2*chg];
            uint2 r11 = *(const uint2*)&ftb[(size_t)(i10 + dx)*64 + 2*chg];

            h2 a00 = u2h(r00.x), b00 = u2h(r00.y);
            h2 a01 = u2h(r01.x), b01 = u2h(r01.y);
            h2 a10 = u2h(r10.x), b10 = u2h(r10.y);
            h2 a11 = u2h(r11.x), b11 = u2h(r11.y);

            float v0 = w00*(float)a00.x + w01*(float)a01.x + w10*(float)a10.x + w11*(float)a11.x;
            float v1 = w00*(float)a00.y + w01*(float)a01.y + w10*(float)a10.y + w11*(float)a11.y;
            float v2 = w00*(float)b00.x + w01*(float)b01.x + w10*(float)b10.x + w11*(float)b11.x;
            float v3 = w00*(float)b00.y + w01*(float)b01.y + w10*(float)b10.y + w11*(float)b11.y;

            uint2 pkd;
            pkd.x = pk2u(v0, v1);
            pkd.y = pk2u(v2, v3);
            *(uint2*)&sl[px*100 + ktl*32 + swz] = pkd;
        }
        __syncthreads();

        // phase B: 6 double-K-blocks x 2 px-tiles, ds_read_b128
        const unsigned* b0p = &sl[(row     )*100 + ksel*4];
        const unsigned* b1p = &sl[(16+row  )*100 + ksel*4];
#pragma unroll
        for (int m = 0; m < 6; ++m) {
            uint4 bv0 = *(const uint4*)&b0p[m*16];
            uint4 bv1 = *(const uint4*)&b1p[m*16];
            U2H waA, waB, s0a, s0b, s1a, s1b;
            waA.u.x = wq[m].x; waA.u.y = wq[m].y;
            waB.u.x = wq[m].z; waB.u.y = wq[m].w;
            s0a.u.x = bv0.x; s0a.u.y = bv0.y;
            s0b.u.x = bv0.z; s0b.u.y = bv0.w;
            s1a.u.x = bv1.x; s1a.u.y = bv1.y;
            s1b.u.x = bv1.z; s1b.u.y = bv1.w;
            acc0 = __builtin_amdgcn_mfma_f32_16x16x16f16(waA.h, s0a.h, acc0, 0, 0, 0);
            acc0 = __builtin_amdgcn_mfma_f32_16x16x16f16(waB.h, s0b.h, acc0, 0, 0, 0);
            acc1 = __builtin_amdgcn_mfma_f32_16x16x16f16(waA.h, s1a.h, acc1, 0, 0, 0);
            acc1 = __builtin_amdgcn_mfma_f32_16x16x16f16(waB.h, s1b.h, acc1, 0, 0, 0);
        }
        __syncthreads();
    }

    int obase = ((b*CC) << 14) + (y << 7) + xq*32;
#pragma unroll
    for (int rI = 0; rI < 4; ++rI) {
        int och = wv*16 + ksel*4 + rI;
        aligned[obase + (och << 14) + row]      = acc0[rI];
        aligned[obase + (och << 14) + 16 + row] = acc1[rI];
    }
}

// ---------------- K3: per-channel partial sum / sumsq; grid 256 = (c, bimg)
__global__ __launch_bounds__(256) void k3_stats(
    const float* __restrict__ a, float* __restrict__ stats)
{
    int c = blockIdx.x & 63;
    int bimg = blockIdx.x >> 6;
    int tid = threadIdx.x;
    float s = 0.f, s2 = 0.f;
    const float* base = a + ((size_t)(bimg*CC + c) << 14);
    for (int i = tid*4; i < HWP; i += 256*4) {
        float4 v = *(const float4*)&base[i];
        s  += v.x + v.y + v.z + v.w;
        s2 += v.x*v.x + v.y*v.y + v.z*v.z + v.w*v.w;
    }
    for (int off = 32; off > 0; off >>= 1) {
        s  += __shfl_down(s,  off, 64);
        s2 += __shfl_down(s2, off, 64);
    }
    __shared__ float rs[4], rs2[4];
    int w = tid >> 6;
    if ((tid & 63) == 0) { rs[w] = s; rs2[w] = s2; }
    __syncthreads();
    if (tid == 0) {
        stats[bimg*128 + c]      = rs[0] + rs[1] + rs[2] + rs[3];
        stats[bimg*128 + 64 + c] = rs2[0] + rs2[1] + rs2[2] + rs2[3];
    }
}

// ---------------- K4: in-place normalize + affine (combines 4 partials)
__global__ __launch_bounds__(256) void k4_norm(
    float* __restrict__ a, const float* __restrict__ stats,
    const float* __restrict__ gamma, const float* __restrict__ beta)
{
    const float invN = 1.f / 65536.f;
    int n4 = (BB*CC*HWP) / 4;
    for (int i4 = blockIdx.x*256 + threadIdx.x; i4 < n4; i4 += gridDim.x*256) {
        int c = (i4 >> 12) & 63;
        float sm  = stats[c] + stats[128+c] + stats[256+c] + stats[384+c];
        float sq  = stats[64+c] + stats[192+c] + stats[320+c] + stats[448+c];
        float mean = sm * invN;
        float var  = sq * invN - mean*mean;
        float sc = gamma[c] * rsqrtf(var + 1e-5f);
        float sh = beta[c] - mean*sc;
        float4 v = ((const float4*)a)[i4];
        v.x = v.x*sc + sh; v.y = v.y*sc + sh;
        v.z = v.z*sc + sh; v.w = v.w*sc + sh;
        ((float4*)a)[i4] = v;
    }
}

extern "C" void kernel_launch(void* const* d_in, const int* in_sizes, int n_in,
                              void* d_out, int out_size, void* d_ws, size_t ws_size,
                              hipStream_t stream)
{
    const float* f1    = (const float*)d_in[0];
    const float* f3    = (const float*)d_in[1];
    const float* ow    = (const float*)d_in[2];
    const float* ob    = (const float*)d_in[3];
    const float* mw    = (const float*)d_in[4];
    const float* gamma = (const float*)d_in[5];
    const float* beta  = (const float*)d_in[6];
    float* out = (float*)d_out;

    float* om     = (float*)d_ws;                 // [4][27][128][128] = 7,077,888 B
    float* stats  = om + 4*27*HWP;                // [512] floats
    unsigned* wmf = (unsigned*)(stats + 512);     // 18432 u32
    unsigned* wof = wmf + 18432;                  // 18432 u32
    unsigned* f13t = wof + 18432;                 // [4][128][128][64] u32 = 16 MB

    const int lds2 = (864 + 32*100) * 4;          // 16,256 B
    (void)hipFuncSetAttribute((const void*)k2_deform,
        hipFuncAttributeMaxDynamicSharedMemorySize, lds2);

    hipLaunchKernelGGL(k0_wt, dim3(144), dim3(256), 0, stream, ow, mw, wmf, wof);
    hipLaunchKernelGGL(kT, dim3(512), dim3(256), 0, stream, f1, f3, f13t);
    hipLaunchKernelGGL(k1_offset_conv, dim3(2048), dim3(256), 0, stream,
                       f13t, wof, ob, om);
    hipLaunchKernelGGL(k2_deform, dim3(2048), dim3(256), lds2, stream,
                       f13t, wmf, om, out);
    hipLaunchKernelGGL(k3_stats, dim3(256), dim3(256), 0, stream, out, stats);
    hipLaunchKernelGGL(k4_norm, dim3(2048), dim3(256), 0, stream,
                       out, stats, gamma, beta);
}

// Round 17
// 96.023 us; speedup vs baseline: 2.8271x; 1.0253x over previous
//
#include <hip/hip_runtime.h>
#include <math.h>

#define BB 4
#define CC 64
#define HH 128
#define WW 128
#define HWP 16384

typedef _Float16 h2 __attribute__((ext_vector_type(2)));
typedef _Float16 h4 __attribute__((ext_vector_type(4)));
typedef __fp16  p2 __attribute__((ext_vector_type(2)));   // cvt_pkrtz's return type
typedef float f32x4 __attribute__((ext_vector_type(4)));
union HU { unsigned u; h2 h; p2 p; };
union U2H { uint2 u; h4 h; };
static __device__ __forceinline__ h2 u2h(unsigned x){ HU v; v.u = x; return v.h; }
static __device__ __forceinline__ unsigned h2u(h2 x){ HU v; v.h = x; return v.u; }
static __device__ __forceinline__ unsigned pk2u(float a, float b){
    HU v; v.p = __builtin_amdgcn_cvt_pkrtz(a, b); return v.u;
}

// ---------------- kT: build f13t[b][y][x][64 pairs u32] (f16 channel pairs).
// pairs 0..31 = f1 channels (2cp,2cp+1); pairs 32..63 = f3 channels.
__global__ __launch_bounds__(256) void kT(
    const float* __restrict__ f1, const float* __restrict__ f3,
    unsigned* __restrict__ f13t)
{
    __shared__ float lt[64*129];
    int b = blockIdx.x >> 7, y = blockIdx.x & 127;
    int t = threadIdx.x;
    unsigned* dst = f13t + ((size_t)((b << 14) + (y << 7)))*64;
    for (int half = 0; half < 2; ++half) {
        const float* src = (half == 0 ? f1 : f3) + (((size_t)b*64) << 14) + (y << 7);
#pragma unroll 4
        for (int i = 0; i < 32; ++i) {
            int idx = i*256 + t; int c = idx >> 7, x = idx & 127;
            lt[c*129 + x] = src[(c << 14) + x];
        }
        __syncthreads();
#pragma unroll 4
        for (int i = 0; i < 16; ++i) {
            int idx = i*256 + t; int x = idx >> 5, cp = idx & 31;
            dst[x*64 + half*32 + cp] = pk2u(lt[(2*cp)*129 + x], lt[(2*cp+1)*129 + x]);
        }
        __syncthreads();
    }
}

// ---------------- K0: pack weights into MFMA A-fragments.
// wmf (k2): u32 idx ((r*64+l)*36+kb)*2+j; P = kb*8+(l>>4)*2+j, kt = P>>5,
//   cp = P&31 (f1 pairs); out-ch r*16+(l&15).
// wof (k1): u32 idx ((mt*64+l)*72+kb)*2+j; P = kb*8+(l>>4)*2+j in [0,576);
//   kt = P>>6, cp = P&63 (concat pair); och = mt*16+(l&15), zero if och>=27.
__global__ __launch_bounds__(256) void k0_wt(
    const float* __restrict__ ow, const float* __restrict__ mw,
    unsigned* __restrict__ wmf, unsigned* __restrict__ wof)
{
    int i = blockIdx.x*256 + threadIdx.x;
    if (i < 18432) {                           // wmf: 4*64*36*2
        int j   = i & 1;
        int t2  = i >> 1;
        int kb  = t2 % 36;
        int rl  = t2 / 36;
        int l   = rl & 63;
        int r   = rl >> 6;
        int row = l & 15, ksel = l >> 4;
        int och = r*16 + row;
        int P   = kb*8 + ksel*2 + j;           // 0..287
        int kt  = P >> 5;
        int cp  = P & 31;
        float lo = mw[och*576 + (2*cp    )*9 + kt];
        float hi = mw[och*576 + (2*cp + 1)*9 + kt];
        wmf[i] = pk2u(lo, hi);
    } else if (i < 36864) {                    // wof: 2*64*72*2
        int idx = i - 18432;
        int j   = idx & 1;
        int t2  = idx >> 1;
        int kb  = t2 % 72;
        int rl  = t2 / 72;
        int l   = rl & 63;
        int mt  = rl >> 6;
        int row = l & 15, ksel = l >> 4;
        int och = mt*16 + row;
        int P   = kb*8 + ksel*2 + j;           // 0..575
        int kt  = P >> 6;                      // tap 0..8
        int cp  = P & 63;                      // concat pair
        unsigned v = 0;
        if (och < 27) {
            float lo = ow[(och*128 + 2*cp    )*9 + kt];
            float hi = ow[(och*128 + 2*cp + 1)*9 + kt];
            v = pk2u(lo, hi);
        }
        wof[idx] = v;
    }
}

// ---------------- K1: offset conv via MFMA. block = quarter-row (32 px),
// 4 waves = 2 M-tiles x 2 px-tiles; K = 576 pairs in 3 tap-row chunks.
__global__ __launch_bounds__(256) void k1_offset_conv(
    const unsigned* __restrict__ f13t, const unsigned* __restrict__ wof,
    const float* __restrict__ ob, float* __restrict__ om)
{
    __shared__ unsigned tile[34*68];

    int blk = blockIdx.x;        // b(2) y(7) xq(2)
    int xq = blk & 3;
    int y  = (blk >> 2) & 127;
    int b  = blk >> 9;

    int tid  = threadIdx.x;
    int lane = tid & 63;
    int wv   = tid >> 6;
    int mt   = wv >> 1;          // M-tile (out-ch 16*mt..)
    int pxt  = wv & 1;           // px-tile
    int row  = lane & 15;
    int ksel = lane >> 4;

    f32x4 acc = {0.f, 0.f, 0.f, 0.f};
    const unsigned* wbase = wof + (size_t)(mt*64 + lane)*144;

#pragma unroll 1
    for (int dy = 0; dy < 3; ++dy) {
        int yy = y + dy - 1;
        bool yok = (unsigned)yy < (unsigned)HH;
        __syncthreads();
        for (int i = tid; i < 544; i += 256) {
            int px34 = i >> 4, q = i & 15;
            int gxp = xq*32 - 1 + px34;
            uint4 v = make_uint4(0u, 0u, 0u, 0u);
            if (yok && (unsigned)gxp < (unsigned)WW)
                v = *(const uint4*)&f13t[(((size_t)(b*128 + yy))*128 + gxp)*64 + q*4];
            *(uint4*)&tile[px34*68 + q*4] = v;
        }
        __syncthreads();

#pragma unroll
        for (int hf = 0; hf < 2; ++hf) {
            uint4 wq[6];
#pragma unroll
            for (int m = 0; m < 6; ++m)
                wq[m] = *(const uint4*)&wbase[dy*48 + hf*24 + m*4];
#pragma unroll
            for (int kl = 0; kl < 12; ++kl) {
                int Pl  = (hf*12 + kl)*8 + ksel*2;
                int ktl = Pl >> 6;
                int cp  = Pl & 63;
                U2H wa;
                uint4 q = wq[kl >> 1];
                if (kl & 1) { wa.u.x = q.z; wa.u.y = q.w; }
                else        { wa.u.x = q.x; wa.u.y = q.y; }
                U2H bfr;
                bfr.u = *(const uint2*)&tile[(pxt*16 + row + ktl)*68 + cp];
                acc = __builtin_amdgcn_mfma_f32_16x16x16f16(wa.h, bfr.h, acc, 0, 0, 0);
            }
        }
    }

    int gx = xq*32 + pxt*16 + row;
#pragma unroll
    for (int rI = 0; rI < 4; ++rI) {
        int och = mt*16 + ksel*4 + rI;
        if (och < 27) {
            float v = acc[rI] + ob[och];
            if (och >= 18) v = 1.f / (1.f + __expf(-v));   // mask sigmoid
            om[((b*27 + och) << 14) + (y << 7) + gx] = v;
        }
    }
}

// ---------------- K2: deformable conv. Phase A now packed-f16 (v_pk_fma_f16)
// — same 16-lane groups, uint2 taps, wq-before-A as the proven 40us R16 body.
// Phase B: Q-permuted sl + ds_read_b128 (R16). Epilogue: per-BLOCK stats
// partials (unique addresses, NO atomics — R15 lesson).
// LDS: params 864 + sl[32][100] = 16,256 B.
__global__ __launch_bounds__(256) void k2_deform(
    const unsigned* __restrict__ f13t, const unsigned* __restrict__ wmf,
    const float* __restrict__ om, float* __restrict__ aligned,
    float* __restrict__ part)
{
    extern __shared__ unsigned lds[];
    unsigned* pl_a = lds;            // [9][32] addr|dx<<14|dy<<15
    unsigned* pl_w = lds + 288;      // [9][32] x uint2 {half2(w00,w01), half2(w10,w11)}
    unsigned* sl   = lds + 864;      // [32 px][100] permuted half2 samples

    int blk = blockIdx.x;        // b(2) y(7) xq(2)
    int xq = blk & 3;
    int y  = (blk >> 2) & 127;
    int b  = blk >> 9;

    int tid  = threadIdx.x;
    int lane = tid & 63;
    int wv   = tid >> 6;
    int row  = lane & 15;
    int ksel = lane >> 4;
    int chg  = lane & 15;        // phase-A channel group (4 ch = 2 pairs)
    int ig   = lane >> 4;        // phase-A item subgroup 0..3
    // lane-constant permuted write column for pairs (2chg, 2chg+1):
    int swz  = ((chg >> 3) << 4) | ((chg & 3) << 2) | (((chg >> 2) & 1) << 1);

    const float* omb = om + ((b*27) << 14) + (y << 7);
    const unsigned* ftb = f13t + (((size_t)b) << 20);

    // ---- param pre-phase: 288 items (k, px)
    for (int i = tid; i < 288; i += 256) {
        int k = i >> 5, lpx = i & 31;
        int gxp = xq*32 + lpx;
        float off0 = omb[((2*k)   << 14) + gxp];
        float off1 = omb[((2*k+1) << 14) + gxp];
        float mk   = omb[((18+k)  << 14) + gxp];   // sigmoided in K1

        float pyf = (float)y   + (float)(k/3) - 1.f + off0;
        float pxg = (float)gxp + (float)(k%3) - 1.f + off1;
        float fy = floorf(pyf), fx = floorf(pxg);
        int y0 = (int)fy, x0 = (int)fx;
        float wy = pyf - fy, wx = pxg - fx;
        float oy = 1.f - wy, ox = 1.f - wx;
        bool yv0 = (unsigned)y0     < (unsigned)HH;
        bool yv1 = (unsigned)(y0+1) < (unsigned)HH;
        bool xv0 = (unsigned)x0     < (unsigned)WW;
        bool xv1 = (unsigned)(x0+1) < (unsigned)WW;
        int y0c = min(max(y0, 0), 127);
        int x0c = min(max(x0, 0), 127);
        int dy = min(max(y0+1, 0), 127) - y0c;   // 0 or 1
        int dx = min(max(x0+1, 0), 127) - x0c;   // 0 or 1
        unsigned a = (unsigned)((y0c << 7) + x0c) | ((unsigned)dx << 14) | ((unsigned)dy << 15);
        float w00 = (yv0 && xv0) ? oy*ox*mk : 0.f;
        float w01 = (yv0 && xv1) ? oy*wx*mk : 0.f;
        float w10 = (yv1 && xv0) ? wy*ox*mk : 0.f;
        float w11 = (yv1 && xv1) ? wy*wx*mk : 0.f;
        pl_a[i] = a;
        pl_w[i*2]     = pk2u(w00, w01);
        pl_w[i*2 + 1] = pk2u(w10, w11);
    }
    __syncthreads();

    f32x4 acc0 = {0.f, 0.f, 0.f, 0.f};
    f32x4 acc1 = {0.f, 0.f, 0.f, 0.f};

    const unsigned* wbase = wmf + (wv*64 + lane)*72;

#pragma unroll 1
    for (int th = 0; th < 3; ++th) {
        uint4 wq[6];
#pragma unroll
        for (int m = 0; m < 6; ++m)
            wq[m] = *(const uint4*)&wbase[th*24 + m*4];

        // phase A: 96 items (ktl,px); lane group of 16 = one item; pk_fma f16
#pragma unroll 2
        for (int it = 0; it < 6; ++it) {
            int item = (it*4 + wv)*4 + ig;     // 0..95
            int ktl  = item >> 5;              // 0..2
            int px   = item & 31;
            int k    = th*3 + ktl;
            int pidx = k*32 + px;
            unsigned a = pl_a[pidx];
            uint2 wpk = *(const uint2*)&pl_w[pidx*2];
            int i00 = (int)(a & 0x3FFFu);
            int dx  = (int)((a >> 14) & 1u);
            int i10 = i00 + (((int)(a >> 15) & 1) << 7);
            h2 hw01 = u2h(wpk.x);
            h2 hw23 = u2h(wpk.y);
            h2 w00d = {hw01.x, hw01.x}, w01d = {hw01.y, hw01.y};
            h2 w10d = {hw23.x, hw23.x}, w11d = {hw23.y, hw23.y};

            uint2 r00 = *(const uint2*)&ftb[(size_t)(i00     )*64 + 2*chg];
            uint2 r01 = *(const uint2*)&ftb[(size_t)(i00 + dx)*64 + 2*chg];
            uint2 r10 = *(const uint2*)&ftb[(size_t)(i10     )*64 + 2*chg];
            uint2 r11 = *(const uint2*)&ftb[(size_t)(i10 + dx)*64 + 2*chg];

            h2 v0 = u2h(r00.x)*w00d + u2h(r01.x)*w01d + u2h(r10.x)*w10d + u2h(r11.x)*w11d;
            h2 v1 = u2h(r00.y)*w00d + u2h(r01.y)*w01d + u2h(r10.y)*w10d + u2h(r11.y)*w11d;

            uint2 pkd;
            pkd.x = h2u(v0);
            pkd.y = h2u(v1);
            *(uint2*)&sl[px*100 + ktl*32 + swz] = pkd;
        }
        __syncthreads();

        // phase B: 6 double-K-blocks x 2 px-tiles, ds_read_b128
        const unsigned* b0p = &sl[(row     )*100 + ksel*4];
        const unsigned* b1p = &sl[(16+row  )*100 + ksel*4];
#pragma unroll
        for (int m = 0; m < 6; ++m) {
            uint4 bv0 = *(const uint4*)&b0p[m*16];
            uint4 bv1 = *(const uint4*)&b1p[m*16];
            U2H waA, waB, s0a, s0b, s1a, s1b;
            waA.u.x = wq[m].x; waA.u.y = wq[m].y;
            waB.u.x = wq[m].z; waB.u.y = wq[m].w;
            s0a.u.x = bv0.x; s0a.u.y = bv0.y;
            s0b.u.x = bv0.z; s0b.u.y = bv0.w;
            s1a.u.x = bv1.x; s1a.u.y = bv1.y;
            s1b.u.x = bv1.z; s1b.u.y = bv1.w;
            acc0 = __builtin_amdgcn_mfma_f32_16x16x16f16(waA.h, s0a.h, acc0, 0, 0, 0);
            acc0 = __builtin_amdgcn_mfma_f32_16x16x16f16(waB.h, s0b.h, acc0, 0, 0, 0);
            acc1 = __builtin_amdgcn_mfma_f32_16x16x16f16(waA.h, s1a.h, acc1, 0, 0, 0);
            acc1 = __builtin_amdgcn_mfma_f32_16x16x16f16(waB.h, s1b.h, acc1, 0, 0, 0);
        }
        __syncthreads();
    }

    // write aligned + per-block stats partials (no atomics; unique addresses)
    float* sred = (float*)lds;   // reuse (safe: past last barrier, sl dead)
    int obase = ((b*CC) << 14) + (y << 7) + xq*32;
#pragma unroll
    for (int rI = 0; rI < 4; ++rI) {
        int och = wv*16 + ksel*4 + rI;
        float v0 = acc0[rI], v1 = acc1[rI];
        aligned[obase + (och << 14) + row]      = v0;
        aligned[obase + (och << 14) + 16 + row] = v1;
        float s  = v0 + v1;
        float sq = v0*v0 + v1*v1;
#pragma unroll
        for (int off = 1; off < 16; off <<= 1) {
            s  += __shfl_xor(s,  off, 64);
            sq += __shfl_xor(sq, off, 64);
        }
        if (row == 0) { sred[och] = s; sred[64 + och] = sq; }
    }
    __syncthreads();
    for (int i = tid; i < 128; i += 256)
        part[(size_t)blk*128 + i] = sred[i];
}

// ---------------- K3b: reduce 2048 per-block partials -> stats[128]
__global__ __launch_bounds__(256) void k3b_reduce(
    const float* __restrict__ part, float* __restrict__ stats)
{
    int i = blockIdx.x;           // 0..127
    int tid = threadIdx.x;
    float s = 0.f;
    for (int j = tid; j < 2048; j += 256) s += part[(size_t)j*128 + i];
    for (int off = 32; off > 0; off >>= 1) s += __shfl_down(s, off, 64);
    __shared__ float rs[4];
    int w = tid >> 6;
    if ((tid & 63) == 0) rs[w] = s;
    __syncthreads();
    if (tid == 0) stats[i] = rs[0] + rs[1] + rs[2] + rs[3];
}

// ---------------- K4: in-place normalize + affine
__global__ __launch_bounds__(256) void k4_norm(
    float* __restrict__ a, const float* __restrict__ stats,
    const float* __restrict__ gamma, const float* __restrict__ beta)
{
    const float invN = 1.f / 65536.f;
    int n4 = (BB*CC*HWP) / 4;
    for (int i4 = blockIdx.x*256 + threadIdx.x; i4 < n4; i4 += gridDim.x*256) {
        int c = (i4 >> 12) & 63;
        float mean = stats[c] * invN;
        float var  = stats[64 + c] * invN - mean*mean;
        float sc = gamma[c] * rsqrtf(var + 1e-5f);
        float sh = beta[c] - mean*sc;
        float4 v = ((const float4*)a)[i4];
        v.x = v.x*sc + sh; v.y = v.y*sc + sh;
        v.z = v.z*sc + sh; v.w = v.w*sc + sh;
        ((float4*)a)[i4] = v;
    }
}

extern "C" void kernel_launch(void* const* d_in, const int* in_sizes, int n_in,
                              void* d_out, int out_size, void* d_ws, size_t ws_size,
                              hipStream_t stream)
{
    const float* f1    = (const float*)d_in[0];
    const float* f3    = (const float*)d_in[1];
    const float* ow    = (const float*)d_in[2];
    const float* ob    = (const float*)d_in[3];
    const float* mw    = (const float*)d_in[4];
    const float* gamma = (const float*)d_in[5];
    const float* beta  = (const float*)d_in[6];
    float* out = (float*)d_out;

    float* om     = (float*)d_ws;                 // [4][27][128][128] = 7,077,888 B
    float* stats  = om + 4*27*HWP;                // [128] floats (512 reserved)
    unsigned* wmf = (unsigned*)(stats + 512);     // 18432 u32
    unsigned* wof = wmf + 18432;                  // 18432 u32
    unsigned* f13t = wof + 18432;                 // [4][128][128][64] u32 = 16 MB
    float* part   = (float*)(f13t + 4*HWP*64);    // [2048][128] = 1 MB

    const int lds2 = (864 + 32*100) * 4;          // 16,256 B
    (void)hipFuncSetAttribute((const void*)k2_deform,
        hipFuncAttributeMaxDynamicSharedMemorySize, lds2);

    hipLaunchKernelGGL(k0_wt, dim3(144), dim3(256), 0, stream, ow, mw, wmf, wof);
    hipLaunchKernelGGL(kT, dim3(512), dim3(256), 0, stream, f1, f3, f13t);
    hipLaunchKernelGGL(k1_offset_conv, dim3(2048), dim3(256), 0, stream,
                       f13t, wof, ob, om);
    hipLaunchKernelGGL(k2_deform, dim3(2048), dim3(256), lds2, stream,
                       f13t, wmf, om, out, part);
    hipLaunchKernelGGL(k3b_reduce, dim3(128), dim3(256), 0, stream, part, stats);
    hipLaunchKernelGGL(k4_norm, dim3(2048), dim3(256), 0, stream,
                       out, stats, gamma, beta);
}

// Round 18
// 89.209 us; speedup vs baseline: 3.0430x; 1.0764x over previous
//
#include <hip/hip_runtime.h>
#include <math.h>

#define BB 4
#define CC 64
#define HH 128
#define WW 128
#define HWP 16384

typedef _Float16 h2 __attribute__((ext_vector_type(2)));
typedef _Float16 h4 __attribute__((ext_vector_type(4)));
typedef __fp16  p2 __attribute__((ext_vector_type(2)));   // cvt_pkrtz's return type
typedef float f32x4 __attribute__((ext_vector_type(4)));
union HU { unsigned u; h2 h; p2 p; };
union U2H { uint2 u; h4 h; };
static __device__ __forceinline__ h2 u2h(unsigned x){ HU v; v.u = x; return v.h; }
static __device__ __forceinline__ unsigned h2u(h2 x){ HU v; v.h = x; return v.u; }
static __device__ __forceinline__ unsigned pk2u(float a, float b){
    HU v; v.p = __builtin_amdgcn_cvt_pkrtz(a, b); return v.u;
}

// ---------------- kT: build f13t[b][y][x][64 pairs u32] (f16 channel pairs).
// pairs 0..31 = f1 channels (2cp,2cp+1); pairs 32..63 = f3 channels.
__global__ __launch_bounds__(256) void kT(
    const float* __restrict__ f1, const float* __restrict__ f3,
    unsigned* __restrict__ f13t)
{
    __shared__ float lt[64*129];
    int b = blockIdx.x >> 7, y = blockIdx.x & 127;
    int t = threadIdx.x;
    unsigned* dst = f13t + ((size_t)((b << 14) + (y << 7)))*64;
    for (int half = 0; half < 2; ++half) {
        const float* src = (half == 0 ? f1 : f3) + (((size_t)b*64) << 14) + (y << 7);
#pragma unroll 4
        for (int i = 0; i < 32; ++i) {
            int idx = i*256 + t; int c = idx >> 7, x = idx & 127;
            lt[c*129 + x] = src[(c << 14) + x];
        }
        __syncthreads();
#pragma unroll 4
        for (int i = 0; i < 16; ++i) {
            int idx = i*256 + t; int x = idx >> 5, cp = idx & 31;
            dst[x*64 + half*32 + cp] = pk2u(lt[(2*cp)*129 + x], lt[(2*cp+1)*129 + x]);
        }
        __syncthreads();
    }
}

// ---------------- K0: pack weights into MFMA A-fragments.
// wmf (k2): u32 idx ((r*64+l)*36+kb)*2+j; P = kb*8+(l>>4)*2+j, kt = P>>5,
//   cp = P&31 (f1 pairs); out-ch r*16+(l&15).
// wof (k1): u32 idx ((mt*64+l)*72+kb)*2+j; P = kb*8+(l>>4)*2+j in [0,576);
//   kt = P>>6, cp = P&63 (concat pair); och = mt*16+(l&15), zero if och>=27.
__global__ __launch_bounds__(256) void k0_wt(
    const float* __restrict__ ow, const float* __restrict__ mw,
    unsigned* __restrict__ wmf, unsigned* __restrict__ wof)
{
    int i = blockIdx.x*256 + threadIdx.x;
    if (i < 18432) {                           // wmf: 4*64*36*2
        int j   = i & 1;
        int t2  = i >> 1;
        int kb  = t2 % 36;
        int rl  = t2 / 36;
        int l   = rl & 63;
        int r   = rl >> 6;
        int row = l & 15, ksel = l >> 4;
        int och = r*16 + row;
        int P   = kb*8 + ksel*2 + j;           // 0..287
        int kt  = P >> 5;
        int cp  = P & 31;
        float lo = mw[och*576 + (2*cp    )*9 + kt];
        float hi = mw[och*576 + (2*cp + 1)*9 + kt];
        wmf[i] = pk2u(lo, hi);
    } else if (i < 36864) {                    // wof: 2*64*72*2
        int idx = i - 18432;
        int j   = idx & 1;
        int t2  = idx >> 1;
        int kb  = t2 % 72;
        int rl  = t2 / 72;
        int l   = rl & 63;
        int mt  = rl >> 6;
        int row = l & 15, ksel = l >> 4;
        int och = mt*16 + row;
        int P   = kb*8 + ksel*2 + j;           // 0..575
        int kt  = P >> 6;                      // tap 0..8
        int cp  = P & 63;                      // concat pair
        unsigned v = 0;
        if (och < 27) {
            float lo = ow[(och*128 + 2*cp    )*9 + kt];
            float hi = ow[(och*128 + 2*cp + 1)*9 + kt];
            v = pk2u(lo, hi);
        }
        wof[idx] = v;
    }
}

// ---------------- K1: offset conv via MFMA. block = quarter-row (32 px),
// 4 waves = 2 M-tiles x 2 px-tiles; K = 576 pairs in 3 tap-row chunks.
__global__ __launch_bounds__(256) void k1_offset_conv(
    const unsigned* __restrict__ f13t, const unsigned* __restrict__ wof,
    const float* __restrict__ ob, float* __restrict__ om)
{
    __shared__ unsigned tile[34*68];

    int blk = blockIdx.x;        // b(2) y(7) xq(2)
    int xq = blk & 3;
    int y  = (blk >> 2) & 127;
    int b  = blk >> 9;

    int tid  = threadIdx.x;
    int lane = tid & 63;
    int wv   = tid >> 6;
    int mt   = wv >> 1;          // M-tile (out-ch 16*mt..)
    int pxt  = wv & 1;           // px-tile
    int row  = lane & 15;
    int ksel = lane >> 4;

    f32x4 acc = {0.f, 0.f, 0.f, 0.f};
    const unsigned* wbase = wof + (size_t)(mt*64 + lane)*144;

#pragma unroll 1
    for (int dy = 0; dy < 3; ++dy) {
        int yy = y + dy - 1;
        bool yok = (unsigned)yy < (unsigned)HH;
        __syncthreads();
        for (int i = tid; i < 544; i += 256) {
            int px34 = i >> 4, q = i & 15;
            int gxp = xq*32 - 1 + px34;
            uint4 v = make_uint4(0u, 0u, 0u, 0u);
            if (yok && (unsigned)gxp < (unsigned)WW)
                v = *(const uint4*)&f13t[(((size_t)(b*128 + yy))*128 + gxp)*64 + q*4];
            *(uint4*)&tile[px34*68 + q*4] = v;
        }
        __syncthreads();

#pragma unroll
        for (int hf = 0; hf < 2; ++hf) {
            uint4 wq[6];
#pragma unroll
            for (int m = 0; m < 6; ++m)
                wq[m] = *(const uint4*)&wbase[dy*48 + hf*24 + m*4];
#pragma unroll
            for (int kl = 0; kl < 12; ++kl) {
                int Pl  = (hf*12 + kl)*8 + ksel*2;
                int ktl = Pl >> 6;
                int cp  = Pl & 63;
                U2H wa;
                uint4 q = wq[kl >> 1];
                if (kl & 1) { wa.u.x = q.z; wa.u.y = q.w; }
                else        { wa.u.x = q.x; wa.u.y = q.y; }
                U2H bfr;
                bfr.u = *(const uint2*)&tile[(pxt*16 + row + ktl)*68 + cp];
                acc = __builtin_amdgcn_mfma_f32_16x16x16f16(wa.h, bfr.h, acc, 0, 0, 0);
            }
        }
    }

    int gx = xq*32 + pxt*16 + row;
#pragma unroll
    for (int rI = 0; rI < 4; ++rI) {
        int och = mt*16 + ksel*4 + rI;
        if (och < 27) {
            float v = acc[rI] + ob[och];
            if (och >= 18) v = 1.f / (1.f + __expf(-v));   // mask sigmoid
            om[((b*27 + och) << 14) + (y << 7) + gx] = v;
        }
    }
}

// ---------------- K2: deformable conv. Phase A: 8-lane groups x uint4 taps
// (halves gather instructions + TA lane-addresses vs R17's 16-lane/uint2 —
// the one R14 piece never isolated; R15 proved R14's regression was atomics).
// Packed-f16 bilinear (R17). Phase B: sigma-permuted sl + ds_read_b128.
// Epilogue: per-BLOCK stats partials (no atomics).
// LDS: params 864 + sl[32][100] = 16,256 B.
__global__ __launch_bounds__(256) void k2_deform(
    const unsigned* __restrict__ f13t, const unsigned* __restrict__ wmf,
    const float* __restrict__ om, float* __restrict__ aligned,
    float* __restrict__ part)
{
    extern __shared__ unsigned lds[];
    unsigned* pl_a = lds;            // [9][32] addr|dx<<14|dy<<15
    unsigned* pl_w = lds + 288;      // [9][32] x uint2 {half2(w00,w01), half2(w10,w11)}
    unsigned* sl   = lds + 864;      // [32 px][100] permuted half2 samples

    int blk = blockIdx.x;        // b(2) y(7) xq(2)
    int xq = blk & 3;
    int y  = (blk >> 2) & 127;
    int b  = blk >> 9;

    int tid  = threadIdx.x;
    int lane = tid & 63;
    int wv   = tid >> 6;
    int row  = lane & 15;
    int ksel = lane >> 4;
    int cg   = tid & 7;          // phase-A channel group (8 ch = 4 pairs: 4cg..4cg+3)
    int grp  = tid >> 3;         // phase-A item group 0..31
    // permuted write base for pairs 4cg..4cg+3: positions {p, p+1, p+4, p+5}
    int pwb  = ((cg >> 2) << 4) | ((cg & 1) << 3) | (((cg >> 1) & 1) << 1);

    const float* omb = om + ((b*27) << 14) + (y << 7);
    const unsigned* ftb = f13t + (((size_t)b) << 20);

    // ---- param pre-phase: 288 items (k, px)
    for (int i = tid; i < 288; i += 256) {
        int k = i >> 5, lpx = i & 31;
        int gxp = xq*32 + lpx;
        float off0 = omb[((2*k)   << 14) + gxp];
        float off1 = omb[((2*k+1) << 14) + gxp];
        float mk   = omb[((18+k)  << 14) + gxp];   // sigmoided in K1

        float pyf = (float)y   + (float)(k/3) - 1.f + off0;
        float pxg = (float)gxp + (float)(k%3) - 1.f + off1;
        float fy = floorf(pyf), fx = floorf(pxg);
        int y0 = (int)fy, x0 = (int)fx;
        float wy = pyf - fy, wx = pxg - fx;
        float oy = 1.f - wy, ox = 1.f - wx;
        bool yv0 = (unsigned)y0     < (unsigned)HH;
        bool yv1 = (unsigned)(y0+1) < (unsigned)HH;
        bool xv0 = (unsigned)x0     < (unsigned)WW;
        bool xv1 = (unsigned)(x0+1) < (unsigned)WW;
        int y0c = min(max(y0, 0), 127);
        int x0c = min(max(x0, 0), 127);
        int dy = min(max(y0+1, 0), 127) - y0c;   // 0 or 1
        int dx = min(max(x0+1, 0), 127) - x0c;   // 0 or 1
        unsigned a = (unsigned)((y0c << 7) + x0c) | ((unsigned)dx << 14) | ((unsigned)dy << 15);
        float w00 = (yv0 && xv0) ? oy*ox*mk : 0.f;
        float w01 = (yv0 && xv1) ? oy*wx*mk : 0.f;
        float w10 = (yv1 && xv0) ? wy*ox*mk : 0.f;
        float w11 = (yv1 && xv1) ? wy*wx*mk : 0.f;
        pl_a[i] = a;
        pl_w[i*2]     = pk2u(w00, w01);
        pl_w[i*2 + 1] = pk2u(w10, w11);
    }
    __syncthreads();

    f32x4 acc0 = {0.f, 0.f, 0.f, 0.f};
    f32x4 acc1 = {0.f, 0.f, 0.f, 0.f};

    const unsigned* wbase = wmf + (wv*64 + lane)*72;

#pragma unroll 1
    for (int th = 0; th < 3; ++th) {
        uint4 wq[6];
#pragma unroll
        for (int m = 0; m < 6; ++m)
            wq[m] = *(const uint4*)&wbase[th*24 + m*4];

        // phase A: 96 items (ktl,px); 8-lane group = one item, 3 items/group
#pragma unroll
        for (int it = 0; it < 3; ++it) {
            int item = it*32 + grp;            // 0..95
            int ktl  = item >> 5;              // 0..2
            int px   = item & 31;
            int k    = th*3 + ktl;
            int pidx = k*32 + px;
            unsigned a = pl_a[pidx];
            uint2 wpk = *(const uint2*)&pl_w[pidx*2];
            int i00 = (int)(a & 0x3FFFu);
            int dx  = (int)((a >> 14) & 1u);
            int i10 = i00 + (((int)(a >> 15) & 1) << 7);
            h2 hw01 = u2h(wpk.x);
            h2 hw23 = u2h(wpk.y);
            h2 w00d = {hw01.x, hw01.x}, w01d = {hw01.y, hw01.y};
            h2 w10d = {hw23.x, hw23.x}, w11d = {hw23.y, hw23.y};

            uint4 t00 = *(const uint4*)&ftb[(size_t)(i00     )*64 + 4*cg];
            uint4 t01 = *(const uint4*)&ftb[(size_t)(i00 + dx)*64 + 4*cg];
            uint4 t10 = *(const uint4*)&ftb[(size_t)(i10     )*64 + 4*cg];
            uint4 t11 = *(const uint4*)&ftb[(size_t)(i10 + dx)*64 + 4*cg];

            h2 v0 = u2h(t00.x)*w00d + u2h(t01.x)*w01d + u2h(t10.x)*w10d + u2h(t11.x)*w11d;
            h2 v1 = u2h(t00.y)*w00d + u2h(t01.y)*w01d + u2h(t10.y)*w10d + u2h(t11.y)*w11d;
            h2 v2 = u2h(t00.z)*w00d + u2h(t01.z)*w01d + u2h(t10.z)*w10d + u2h(t11.z)*w11d;
            h2 v3 = u2h(t00.w)*w00d + u2h(t01.w)*w01d + u2h(t10.w)*w10d + u2h(t11.w)*w11d;

            int bs = px*100 + ktl*32 + pwb;
            *(uint2*)&sl[bs]     = make_uint2(h2u(v0), h2u(v1));
            *(uint2*)&sl[bs + 4] = make_uint2(h2u(v2), h2u(v3));
        }
        __syncthreads();

        // phase B: 6 double-K-blocks x 2 px-tiles, ds_read_b128
        const unsigned* b0p = &sl[(row     )*100 + ksel*4];
        const unsigned* b1p = &sl[(16+row  )*100 + ksel*4];
#pragma unroll
        for (int m = 0; m < 6; ++m) {
            uint4 bv0 = *(const uint4*)&b0p[m*16];
            uint4 bv1 = *(const uint4*)&b1p[m*16];
            U2H waA, waB, s0a, s0b, s1a, s1b;
            waA.u.x = wq[m].x; waA.u.y = wq[m].y;
            waB.u.x = wq[m].z; waB.u.y = wq[m].w;
            s0a.u.x = bv0.x; s0a.u.y = bv0.y;
            s0b.u.x = bv0.z; s0b.u.y = bv0.w;
            s1a.u.x = bv1.x; s1a.u.y = bv1.y;
            s1b.u.x = bv1.z; s1b.u.y = bv1.w;
            acc0 = __builtin_amdgcn_mfma_f32_16x16x16f16(waA.h, s0a.h, acc0, 0, 0, 0);
            acc0 = __builtin_amdgcn_mfma_f32_16x16x16f16(waB.h, s0b.h, acc0, 0, 0, 0);
            acc1 = __builtin_amdgcn_mfma_f32_16x16x16f16(waA.h, s1a.h, acc1, 0, 0, 0);
            acc1 = __builtin_amdgcn_mfma_f32_16x16x16f16(waB.h, s1b.h, acc1, 0, 0, 0);
        }
        __syncthreads();
    }

    // write aligned + per-block stats partials (no atomics; unique addresses)
    float* sred = (float*)lds;   // reuse (safe: past last barrier, sl dead)
    int obase = ((b*CC) << 14) + (y << 7) + xq*32;
#pragma unroll
    for (int rI = 0; rI < 4; ++rI) {
        int och = wv*16 + ksel*4 + rI;
        float v0 = acc0[rI], v1 = acc1[rI];
        aligned[obase + (och << 14) + row]      = v0;
        aligned[obase + (och << 14) + 16 + row] = v1;
        float s  = v0 + v1;
        float sq = v0*v0 + v1*v1;
#pragma unroll
        for (int off = 1; off < 16; off <<= 1) {
            s  += __shfl_xor(s,  off, 64);
            sq += __shfl_xor(sq, off, 64);
        }
        if (row == 0) { sred[och] = s; sred[64 + och] = sq; }
    }
    __syncthreads();
    for (int i = tid; i < 128; i += 256)
        part[(size_t)blk*128 + i] = sred[i];
}

// ---------------- K3b: reduce 2048 per-block partials -> stats[128]
__global__ __launch_bounds__(256) void k3b_reduce(
    const float* __restrict__ part, float* __restrict__ stats)
{
    int i = blockIdx.x;           // 0..127
    int tid = threadIdx.x;
    float s = 0.f;
    for (int j = tid; j < 2048; j += 256) s += part[(size_t)j*128 + i];
    for (int off = 32; off > 0; off >>= 1) s += __shfl_down(s, off, 64);
    __shared__ float rs[4];
    int w = tid >> 6;
    if ((tid & 63) == 0) rs[w] = s;
    __syncthreads();
    if (tid == 0) stats[i] = rs[0] + rs[1] + rs[2] + rs[3];
}

// ---------------- K4: in-place normalize + affine
__global__ __launch_bounds__(256) void k4_norm(
    float* __restrict__ a, const float* __restrict__ stats,
    const float* __restrict__ gamma, const float* __restrict__ beta)
{
    const float invN = 1.f / 65536.f;
    int n4 = (BB*CC*HWP) / 4;
    for (int i4 = blockIdx.x*256 + threadIdx.x; i4 < n4; i4 += gridDim.x*256) {
        int c = (i4 >> 12) & 63;
        float mean = stats[c] * invN;
        float var  = stats[64 + c] * invN - mean*mean;
        float sc = gamma[c] * rsqrtf(var + 1e-5f);
        float sh = beta[c] - mean*sc;
        float4 v = ((const float4*)a)[i4];
        v.x = v.x*sc + sh; v.y = v.y*sc + sh;
        v.z = v.z*sc + sh; v.w = v.w*sc + sh;
        ((float4*)a)[i4] = v;
    }
}

extern "C" void kernel_launch(void* const* d_in, const int* in_sizes, int n_in,
                              void* d_out, int out_size, void* d_ws, size_t ws_size,
                              hipStream_t stream)
{
    const float* f1    = (const float*)d_in[0];
    const float* f3    = (const float*)d_in[1];
    const float* ow    = (const float*)d_in[2];
    const float* ob    = (const float*)d_in[3];
    const float* mw    = (const float*)d_in[4];
    const float* gamma = (const float*)d_in[5];
    const float* beta  = (const float*)d_in[6];
    float* out = (float*)d_out;

    float* om     = (float*)d_ws;                 // [4][27][128][128] = 7,077,888 B
    float* stats  = om + 4*27*HWP;                // [128] floats (512 reserved)
    unsigned* wmf = (unsigned*)(stats + 512);     // 18432 u32
    unsigned* wof = wmf + 18432;                  // 18432 u32
    unsigned* f13t = wof + 18432;                 // [4][128][128][64] u32 = 16 MB
    float* part   = (float*)(f13t + 4*HWP*64);    // [2048][128] = 1 MB

    const int lds2 = (864 + 32*100) * 4;          // 16,256 B
    (void)hipFuncSetAttribute((const void*)k2_deform,
        hipFuncAttributeMaxDynamicSharedMemorySize, lds2);

    hipLaunchKernelGGL(k0_wt, dim3(144), dim3(256), 0, stream, ow, mw, wmf, wof);
    hipLaunchKernelGGL(kT, dim3(512), dim3(256), 0, stream, f1, f3, f13t);
    hipLaunchKernelGGL(k1_offset_conv, dim3(2048), dim3(256), 0, stream,
                       f13t, wof, ob, om);
    hipLaunchKernelGGL(k2_deform, dim3(2048), dim3(256), lds2, stream,
                       f13t, wmf, om, out, part);
    hipLaunchKernelGGL(k3b_reduce, dim3(128), dim3(256), 0, stream, part, stats);
    hipLaunchKernelGGL(k4_norm, dim3(2048), dim3(256), 0, stream,
                       out, stats, gamma, beta);
}

// Round 19
// 79.752 us; speedup vs baseline: 3.4039x; 1.1186x over previous
//
#include <hip/hip_runtime.h>
#include <math.h>

#define BB 4
#define CC 64
#define HH 128
#define WW 128
#define HWP 16384

typedef _Float16 h2 __attribute__((ext_vector_type(2)));
typedef _Float16 h4 __attribute__((ext_vector_type(4)));
typedef __fp16  p2 __attribute__((ext_vector_type(2)));   // cvt_pkrtz's return type
typedef float f32x4 __attribute__((ext_vector_type(4)));
union HU { unsigned u; h2 h; p2 p; };
union U2H { uint2 u; h4 h; };
static __device__ __forceinline__ h2 u2h(unsigned x){ HU v; v.u = x; return v.h; }
static __device__ __forceinline__ unsigned h2u(h2 x){ HU v; v.h = x; return v.u; }
static __device__ __forceinline__ unsigned pk2u(float a, float b){
    HU v; v.p = __builtin_amdgcn_cvt_pkrtz(a, b); return v.u;
}

// ---------------- kTm: merged kT (blocks 0..511) + k0 weight-pack (512..655).
// kT: build f13t[b][y][x][64 pairs u32]; pairs 0..31 = f1, 32..63 = f3.
// k0: wmf (k2 A-frags) + wof (k1 A-frags) — layouts as R18.
__global__ __launch_bounds__(256) void kTm(
    const float* __restrict__ f1, const float* __restrict__ f3,
    const float* __restrict__ ow, const float* __restrict__ mw,
    unsigned* __restrict__ f13t, unsigned* __restrict__ wmf,
    unsigned* __restrict__ wof)
{
    __shared__ float lt[64*129];
    int t = threadIdx.x;
    if (blockIdx.x < 512) {
        int b = blockIdx.x >> 7, y = blockIdx.x & 127;
        unsigned* dst = f13t + ((size_t)((b << 14) + (y << 7)))*64;
        for (int half = 0; half < 2; ++half) {
            const float* src = (half == 0 ? f1 : f3) + (((size_t)b*64) << 14) + (y << 7);
#pragma unroll 4
            for (int i = 0; i < 32; ++i) {
                int idx = i*256 + t; int c = idx >> 7, x = idx & 127;
                lt[c*129 + x] = src[(c << 14) + x];
            }
            __syncthreads();
#pragma unroll 4
            for (int i = 0; i < 16; ++i) {
                int idx = i*256 + t; int x = idx >> 5, cp = idx & 31;
                dst[x*64 + half*32 + cp] = pk2u(lt[(2*cp)*129 + x], lt[(2*cp+1)*129 + x]);
            }
            __syncthreads();
        }
        return;
    }
    int i = (blockIdx.x - 512)*256 + t;
    if (i < 18432) {                           // wmf: 4*64*36*2
        int j   = i & 1;
        int t2  = i >> 1;
        int kb  = t2 % 36;
        int rl  = t2 / 36;
        int l   = rl & 63;
        int r   = rl >> 6;
        int row = l & 15, ksel = l >> 4;
        int och = r*16 + row;
        int P   = kb*8 + ksel*2 + j;           // 0..287
        int kt  = P >> 5;
        int cp  = P & 31;
        float lo = mw[och*576 + (2*cp    )*9 + kt];
        float hi = mw[och*576 + (2*cp + 1)*9 + kt];
        wmf[i] = pk2u(lo, hi);
    } else if (i < 36864) {                    // wof: 2*64*72*2
        int idx = i - 18432;
        int j   = idx & 1;
        int t2  = idx >> 1;
        int kb  = t2 % 72;
        int rl  = t2 / 72;
        int l   = rl & 63;
        int mt  = rl >> 6;
        int row = l & 15, ksel = l >> 4;
        int och = mt*16 + row;
        int P   = kb*8 + ksel*2 + j;           // 0..575
        int kt  = P >> 6;                      // tap 0..8
        int cp  = P & 63;                      // concat pair
        unsigned v = 0;
        if (och < 27) {
            float lo = ow[(och*128 + 2*cp    )*9 + kt];
            float hi = ow[(och*128 + 2*cp + 1)*9 + kt];
            v = pk2u(lo, hi);
        }
        wof[idx] = v;
    }
}

// ---------------- K1: offset conv via MFMA. block = quarter-row (32 px),
// 4 waves = 2 M-tiles x 2 px-tiles; K = 576 pairs in 3 tap-row chunks.
// XCD-aware bijective swizzle: XCD j owns a contiguous 64-row y-window so
// adjacent-y blocks share row slabs in the same private L2.
__global__ __launch_bounds__(256) void k1_offset_conv(
    const unsigned* __restrict__ f13t, const unsigned* __restrict__ wof,
    const float* __restrict__ ob, float* __restrict__ om)
{
    __shared__ unsigned tile[34*68];

    int blk0 = blockIdx.x;
    int blk  = ((blk0 & 7) << 8) | (blk0 >> 3);   // bijective (2048 % 8 == 0)
    int xq = blk & 3;
    int y  = (blk >> 2) & 127;
    int b  = blk >> 9;

    int tid  = threadIdx.x;
    int lane = tid & 63;
    int wv   = tid >> 6;
    int mt   = wv >> 1;          // M-tile (out-ch 16*mt..)
    int pxt  = wv & 1;           // px-tile
    int row  = lane & 15;
    int ksel = lane >> 4;

    f32x4 acc = {0.f, 0.f, 0.f, 0.f};
    const unsigned* wbase = wof + (size_t)(mt*64 + lane)*144;

#pragma unroll 1
    for (int dy = 0; dy < 3; ++dy) {
        int yy = y + dy - 1;
        bool yok = (unsigned)yy < (unsigned)HH;
        __syncthreads();
        for (int i = tid; i < 544; i += 256) {
            int px34 = i >> 4, q = i & 15;
            int gxp = xq*32 - 1 + px34;
            uint4 v = make_uint4(0u, 0u, 0u, 0u);
            if (yok && (unsigned)gxp < (unsigned)WW)
                v = *(const uint4*)&f13t[(((size_t)(b*128 + yy))*128 + gxp)*64 + q*4];
            *(uint4*)&tile[px34*68 + q*4] = v;
        }
        __syncthreads();

#pragma unroll
        for (int hf = 0; hf < 2; ++hf) {
            uint4 wq[6];
#pragma unroll
            for (int m = 0; m < 6; ++m)
                wq[m] = *(const uint4*)&wbase[dy*48 + hf*24 + m*4];
#pragma unroll
            for (int kl = 0; kl < 12; ++kl) {
                int Pl  = (hf*12 + kl)*8 + ksel*2;
                int ktl = Pl >> 6;
                int cp  = Pl & 63;
                U2H wa;
                uint4 q = wq[kl >> 1];
                if (kl & 1) { wa.u.x = q.z; wa.u.y = q.w; }
                else        { wa.u.x = q.x; wa.u.y = q.y; }
                U2H bfr;
                bfr.u = *(const uint2*)&tile[(pxt*16 + row + ktl)*68 + cp];
                acc = __builtin_amdgcn_mfma_f32_16x16x16f16(wa.h, bfr.h, acc, 0, 0, 0);
            }
        }
    }

    int gx = xq*32 + pxt*16 + row;
#pragma unroll
    for (int rI = 0; rI < 4; ++rI) {
        int och = mt*16 + ksel*4 + rI;
        if (och < 27) {
            float v = acc[rI] + ob[och];
            if (och >= 18) v = 1.f / (1.f + __expf(-v));   // mask sigmoid
            om[((b*27 + och) << 14) + (y << 7) + gx] = v;
        }
    }
}

// ---------------- K2: deformable conv (R18 body) + XCD-aware swizzle.
// Phase A: 8-lane groups x uint4 taps, packed-f16 bilinear.
// Phase B: sigma-permuted sl + ds_read_b128. Epilogue: per-block partials.
// LDS: params 864 + sl[32][100] = 16,256 B.
__global__ __launch_bounds__(256) void k2_deform(
    const unsigned* __restrict__ f13t, const unsigned* __restrict__ wmf,
    const float* __restrict__ om, float* __restrict__ aligned,
    float* __restrict__ part)
{
    extern __shared__ unsigned lds[];
    unsigned* pl_a = lds;            // [9][32] addr|dx<<14|dy<<15
    unsigned* pl_w = lds + 288;      // [9][32] x uint2 {half2(w00,w01), half2(w10,w11)}
    unsigned* sl   = lds + 864;      // [32 px][100] permuted half2 samples

    int blk0 = blockIdx.x;
    int blk  = ((blk0 & 7) << 8) | (blk0 >> 3);   // bijective (2048 % 8 == 0)
    int xq = blk & 3;
    int y  = (blk >> 2) & 127;
    int b  = blk >> 9;

    int tid  = threadIdx.x;
    int lane = tid & 63;
    int wv   = tid >> 6;
    int row  = lane & 15;
    int ksel = lane >> 4;
    int cg   = tid & 7;          // phase-A channel group (8 ch = 4 pairs: 4cg..4cg+3)
    int grp  = tid >> 3;         // phase-A item group 0..31
    // permuted write base for pairs 4cg..4cg+3: positions {p, p+1, p+4, p+5}
    int pwb  = ((cg >> 2) << 4) | ((cg & 1) << 3) | (((cg >> 1) & 1) << 1);

    const float* omb = om + ((b*27) << 14) + (y << 7);
    const unsigned* ftb = f13t + (((size_t)b) << 20);

    // ---- param pre-phase: 288 items (k, px)
    for (int i = tid; i < 288; i += 256) {
        int k = i >> 5, lpx = i & 31;
        int gxp = xq*32 + lpx;
        float off0 = omb[((2*k)   << 14) + gxp];
        float off1 = omb[((2*k+1) << 14) + gxp];
        float mk   = omb[((18+k)  << 14) + gxp];   // sigmoided in K1

        float pyf = (float)y   + (float)(k/3) - 1.f + off0;
        float pxg = (float)gxp + (float)(k%3) - 1.f + off1;
        float fy = floorf(pyf), fx = floorf(pxg);
        int y0 = (int)fy, x0 = (int)fx;
        float wy = pyf - fy, wx = pxg - fx;
        float oy = 1.f - wy, ox = 1.f - wx;
        bool yv0 = (unsigned)y0     < (unsigned)HH;
        bool yv1 = (unsigned)(y0+1) < (unsigned)HH;
        bool xv0 = (unsigned)x0     < (unsigned)WW;
        bool xv1 = (unsigned)(x0+1) < (unsigned)WW;
        int y0c = min(max(y0, 0), 127);
        int x0c = min(max(x0, 0), 127);
        int dy = min(max(y0+1, 0), 127) - y0c;   // 0 or 1
        int dx = min(max(x0+1, 0), 127) - x0c;   // 0 or 1
        unsigned a = (unsigned)((y0c << 7) + x0c) | ((unsigned)dx << 14) | ((unsigned)dy << 15);
        float w00 = (yv0 && xv0) ? oy*ox*mk : 0.f;
        float w01 = (yv0 && xv1) ? oy*wx*mk : 0.f;
        float w10 = (yv1 && xv0) ? wy*ox*mk : 0.f;
        float w11 = (yv1 && xv1) ? wy*wx*mk : 0.f;
        pl_a[i] = a;
        pl_w[i*2]     = pk2u(w00, w01);
        pl_w[i*2 + 1] = pk2u(w10, w11);
    }
    __syncthreads();

    f32x4 acc0 = {0.f, 0.f, 0.f, 0.f};
    f32x4 acc1 = {0.f, 0.f, 0.f, 0.f};

    const unsigned* wbase = wmf + (wv*64 + lane)*72;

#pragma unroll 1
    for (int th = 0; th < 3; ++th) {
        uint4 wq[6];
#pragma unroll
        for (int m = 0; m < 6; ++m)
            wq[m] = *(const uint4*)&wbase[th*24 + m*4];

        // phase A: 96 items (ktl,px); 8-lane group = one item, 3 items/group
#pragma unroll
        for (int it = 0; it < 3; ++it) {
            int item = it*32 + grp;            // 0..95
            int ktl  = item >> 5;              // 0..2
            int px   = item & 31;
            int k    = th*3 + ktl;
            int pidx = k*32 + px;
            unsigned a = pl_a[pidx];
            uint2 wpk = *(const uint2*)&pl_w[pidx*2];
            int i00 = (int)(a & 0x3FFFu);
            int dx  = (int)((a >> 14) & 1u);
            int i10 = i00 + (((int)(a >> 15) & 1) << 7);
            h2 hw01 = u2h(wpk.x);
            h2 hw23 = u2h(wpk.y);
            h2 w00d = {hw01.x, hw01.x}, w01d = {hw01.y, hw01.y};
            h2 w10d = {hw23.x, hw23.x}, w11d = {hw23.y, hw23.y};

            uint4 t00 = *(const uint4*)&ftb[(size_t)(i00     )*64 + 4*cg];
            uint4 t01 = *(const uint4*)&ftb[(size_t)(i00 + dx)*64 + 4*cg];
            uint4 t10 = *(const uint4*)&ftb[(size_t)(i10     )*64 + 4*cg];
            uint4 t11 = *(const uint4*)&ftb[(size_t)(i10 + dx)*64 + 4*cg];

            h2 v0 = u2h(t00.x)*w00d + u2h(t01.x)*w01d + u2h(t10.x)*w10d + u2h(t11.x)*w11d;
            h2 v1 = u2h(t00.y)*w00d + u2h(t01.y)*w01d + u2h(t10.y)*w10d + u2h(t11.y)*w11d;
            h2 v2 = u2h(t00.z)*w00d + u2h(t01.z)*w01d + u2h(t10.z)*w10d + u2h(t11.z)*w11d;
            h2 v3 = u2h(t00.w)*w00d + u2h(t01.w)*w01d + u2h(t10.w)*w10d + u2h(t11.w)*w11d;

            int bs = px*100 + ktl*32 + pwb;
            *(uint2*)&sl[bs]     = make_uint2(h2u(v0), h2u(v1));
            *(uint2*)&sl[bs + 4] = make_uint2(h2u(v2), h2u(v3));
        }
        __syncthreads();

        // phase B: 6 double-K-blocks x 2 px-tiles, ds_read_b128
        const unsigned* b0p = &sl[(row     )*100 + ksel*4];
        const unsigned* b1p = &sl[(16+row  )*100 + ksel*4];
#pragma unroll
        for (int m = 0; m < 6; ++m) {
            uint4 bv0 = *(const uint4*)&b0p[m*16];
            uint4 bv1 = *(const uint4*)&b1p[m*16];
            U2H waA, waB, s0a, s0b, s1a, s1b;
            waA.u.x = wq[m].x; waA.u.y = wq[m].y;
            waB.u.x = wq[m].z; waB.u.y = wq[m].w;
            s0a.u.x = bv0.x; s0a.u.y = bv0.y;
            s0b.u.x = bv0.z; s0b.u.y = bv0.w;
            s1a.u.x = bv1.x; s1a.u.y = bv1.y;
            s1b.u.x = bv1.z; s1b.u.y = bv1.w;
            acc0 = __builtin_amdgcn_mfma_f32_16x16x16f16(waA.h, s0a.h, acc0, 0, 0, 0);
            acc0 = __builtin_amdgcn_mfma_f32_16x16x16f16(waB.h, s0b.h, acc0, 0, 0, 0);
            acc1 = __builtin_amdgcn_mfma_f32_16x16x16f16(waA.h, s1a.h, acc1, 0, 0, 0);
            acc1 = __builtin_amdgcn_mfma_f32_16x16x16f16(waB.h, s1b.h, acc1, 0, 0, 0);
        }
        __syncthreads();
    }

    // write aligned + per-block stats partials (no atomics; unique addresses)
    float* sred = (float*)lds;   // reuse (safe: past last barrier, sl dead)
    int obase = ((b*CC) << 14) + (y << 7) + xq*32;
#pragma unroll
    for (int rI = 0; rI < 4; ++rI) {
        int och = wv*16 + ksel*4 + rI;
        float v0 = acc0[rI], v1 = acc1[rI];
        aligned[obase + (och << 14) + row]      = v0;
        aligned[obase + (och << 14) + 16 + row] = v1;
        float s  = v0 + v1;
        float sq = v0*v0 + v1*v1;
#pragma unroll
        for (int off = 1; off < 16; off <<= 1) {
            s  += __shfl_xor(s,  off, 64);
            sq += __shfl_xor(sq, off, 64);
        }
        if (row == 0) { sred[och] = s; sred[64 + och] = sq; }
    }
    __syncthreads();
    for (int i = tid; i < 128; i += 256)
        part[(size_t)blk*128 + i] = sred[i];
}

// ---------------- K3b: reduce 2048 per-block partials -> stats[128]
__global__ __launch_bounds__(256) void k3b_reduce(
    const float* __restrict__ part, float* __restrict__ stats)
{
    int i = blockIdx.x;           // 0..127
    int tid = threadIdx.x;
    float s = 0.f;
    for (int j = tid; j < 2048; j += 256) s += part[(size_t)j*128 + i];
    for (int off = 32; off > 0; off >>= 1) s += __shfl_down(s, off, 64);
    __shared__ float rs[4];
    int w = tid >> 6;
    if ((tid & 63) == 0) rs[w] = s;
    __syncthreads();
    if (tid == 0) stats[i] = rs[0] + rs[1] + rs[2] + rs[3];
}

// ---------------- K4: in-place normalize + affine
__global__ __launch_bounds__(256) void k4_norm(
    float* __restrict__ a, const float* __restrict__ stats,
    const float* __restrict__ gamma, const float* __restrict__ beta)
{
    const float invN = 1.f / 65536.f;
    int n4 = (BB*CC*HWP) / 4;
    for (int i4 = blockIdx.x*256 + threadIdx.x; i4 < n4; i4 += gridDim.x*256) {
        int c = (i4 >> 12) & 63;
        float mean = stats[c] * invN;
        float var  = stats[64 + c] * invN - mean*mean;
        float sc = gamma[c] * rsqrtf(var + 1e-5f);
        float sh = beta[c] - mean*sc;
        float4 v = ((const float4*)a)[i4];
        v.x = v.x*sc + sh; v.y = v.y*sc + sh;
        v.z = v.z*sc + sh; v.w = v.w*sc + sh;
        ((float4*)a)[i4] = v;
    }
}

extern "C" void kernel_launch(void* const* d_in, const int* in_sizes, int n_in,
                              void* d_out, int out_size, void* d_ws, size_t ws_size,
                              hipStream_t stream)
{
    const float* f1    = (const float*)d_in[0];
    const float* f3    = (const float*)d_in[1];
    const float* ow    = (const float*)d_in[2];
    const float* ob    = (const float*)d_in[3];
    const float* mw    = (const float*)d_in[4];
    const float* gamma = (const float*)d_in[5];
    const float* beta  = (const float*)d_in[6];
    float* out = (float*)d_out;

    float* om     = (float*)d_ws;                 // [4][27][128][128] = 7,077,888 B
    float* stats  = om + 4*27*HWP;                // [128] floats (512 reserved)
    unsigned* wmf = (unsigned*)(stats + 512);     // 18432 u32
    unsigned* wof = wmf + 18432;                  // 18432 u32
    unsigned* f13t = wof + 18432;                 // [4][128][128][64] u32 = 16 MB
    float* part   = (float*)(f13t + 4*HWP*64);    // [2048][128] = 1 MB

    const int lds2 = (864 + 32*100) * 4;          // 16,256 B
    (void)hipFuncSetAttribute((const void*)k2_deform,
        hipFuncAttributeMaxDynamicSharedMemorySize, lds2);

    hipLaunchKernelGGL(kTm, dim3(656), dim3(256), 0, stream,
                       f1, f3, ow, mw, f13t, wmf, wof);
    hipLaunchKernelGGL(k1_offset_conv, dim3(2048), dim3(256), 0, stream,
                       f13t, wof, ob, om);
    hipLaunchKernelGGL(k2_deform, dim3(2048), dim3(256), lds2, stream,
                       f13t, wmf, om, out, part);
    hipLaunchKernelGGL(k3b_reduce, dim3(128), dim3(256), 0, stream, part, stats);
    hipLaunchKernelGGL(k4_norm, dim3(2048), dim3(256), 0, stream,
                       out, stats, gamma, beta);
}

// Round 20
// 78.375 us; speedup vs baseline: 3.4637x; 1.0176x over previous
//
#include <hip/hip_runtime.h>
#include <math.h>

#define BB 4
#define CC 64
#define HH 128
#define WW 128
#define HWP 16384

typedef _Float16 h2 __attribute__((ext_vector_type(2)));
typedef _Float16 h4 __attribute__((ext_vector_type(4)));
typedef __fp16  p2 __attribute__((ext_vector_type(2)));   // cvt_pkrtz's return type
typedef float f32x4 __attribute__((ext_vector_type(4)));
union HU { unsigned u; h2 h; p2 p; };
union U2H { uint2 u; h4 h; };
static __device__ __forceinline__ h2 u2h(unsigned x){ HU v; v.u = x; return v.h; }
static __device__ __forceinline__ unsigned h2u(h2 x){ HU v; v.h = x; return v.u; }
static __device__ __forceinline__ unsigned pk2u(float a, float b){
    HU v; v.p = __builtin_amdgcn_cvt_pkrtz(a, b); return v.u;
}

// ---------------- kTm: merged kT (blocks 0..511) + k0 weight-pack (512..655).
__global__ __launch_bounds__(256) void kTm(
    const float* __restrict__ f1, const float* __restrict__ f3,
    const float* __restrict__ ow, const float* __restrict__ mw,
    unsigned* __restrict__ f13t, unsigned* __restrict__ wmf,
    unsigned* __restrict__ wof)
{
    __shared__ float lt[64*129];
    int t = threadIdx.x;
    if (blockIdx.x < 512) {
        int b = blockIdx.x >> 7, y = blockIdx.x & 127;
        unsigned* dst = f13t + ((size_t)((b << 14) + (y << 7)))*64;
        for (int half = 0; half < 2; ++half) {
            const float* src = (half == 0 ? f1 : f3) + (((size_t)b*64) << 14) + (y << 7);
#pragma unroll 4
            for (int i = 0; i < 32; ++i) {
                int idx = i*256 + t; int c = idx >> 7, x = idx & 127;
                lt[c*129 + x] = src[(c << 14) + x];
            }
            __syncthreads();
#pragma unroll 4
            for (int i = 0; i < 16; ++i) {
                int idx = i*256 + t; int x = idx >> 5, cp = idx & 31;
                dst[x*64 + half*32 + cp] = pk2u(lt[(2*cp)*129 + x], lt[(2*cp+1)*129 + x]);
            }
            __syncthreads();
        }
        return;
    }
    int i = (blockIdx.x - 512)*256 + t;
    if (i < 18432) {                           // wmf: 4*64*36*2
        int j   = i & 1;
        int t2  = i >> 1;
        int kb  = t2 % 36;
        int rl  = t2 / 36;
        int l   = rl & 63;
        int r   = rl >> 6;
        int row = l & 15, ksel = l >> 4;
        int och = r*16 + row;
        int P   = kb*8 + ksel*2 + j;           // 0..287
        int kt  = P >> 5;
        int cp  = P & 31;
        float lo = mw[och*576 + (2*cp    )*9 + kt];
        float hi = mw[och*576 + (2*cp + 1)*9 + kt];
        wmf[i] = pk2u(lo, hi);
    } else if (i < 36864) {                    // wof: 2*64*72*2
        int idx = i - 18432;
        int j   = idx & 1;
        int t2  = idx >> 1;
        int kb  = t2 % 72;
        int rl  = t2 / 72;
        int l   = rl & 63;
        int mt  = rl >> 6;
        int row = l & 15, ksel = l >> 4;
        int och = mt*16 + row;
        int P   = kb*8 + ksel*2 + j;           // 0..575
        int kt  = P >> 6;                      // tap 0..8
        int cp  = P & 63;                      // concat pair
        unsigned v = 0;
        if (och < 27) {
            float lo = ow[(och*128 + 2*cp    )*9 + kt];
            float hi = ow[(och*128 + 2*cp + 1)*9 + kt];
            v = pk2u(lo, hi);
        }
        wof[idx] = v;
    }
}

// ---------------- K1: offset conv via MFMA, XCD-swizzled (R19).
__global__ __launch_bounds__(256) void k1_offset_conv(
    const unsigned* __restrict__ f13t, const unsigned* __restrict__ wof,
    const float* __restrict__ ob, float* __restrict__ om)
{
    __shared__ unsigned tile[34*68];

    int blk0 = blockIdx.x;
    int blk  = ((blk0 & 7) << 8) | (blk0 >> 3);   // bijective (2048 % 8 == 0)
    int xq = blk & 3;
    int y  = (blk >> 2) & 127;
    int b  = blk >> 9;

    int tid  = threadIdx.x;
    int lane = tid & 63;
    int wv   = tid >> 6;
    int mt   = wv >> 1;          // M-tile (out-ch 16*mt..)
    int pxt  = wv & 1;           // px-tile
    int row  = lane & 15;
    int ksel = lane >> 4;

    f32x4 acc = {0.f, 0.f, 0.f, 0.f};
    const unsigned* wbase = wof + (size_t)(mt*64 + lane)*144;

#pragma unroll 1
    for (int dy = 0; dy < 3; ++dy) {
        int yy = y + dy - 1;
        bool yok = (unsigned)yy < (unsigned)HH;
        __syncthreads();
        for (int i = tid; i < 544; i += 256) {
            int px34 = i >> 4, q = i & 15;
            int gxp = xq*32 - 1 + px34;
            uint4 v = make_uint4(0u, 0u, 0u, 0u);
            if (yok && (unsigned)gxp < (unsigned)WW)
                v = *(const uint4*)&f13t[(((size_t)(b*128 + yy))*128 + gxp)*64 + q*4];
            *(uint4*)&tile[px34*68 + q*4] = v;
        }
        __syncthreads();

#pragma unroll
        for (int hf = 0; hf < 2; ++hf) {
            uint4 wq[6];
#pragma unroll
            for (int m = 0; m < 6; ++m)
                wq[m] = *(const uint4*)&wbase[dy*48 + hf*24 + m*4];
#pragma unroll
            for (int kl = 0; kl < 12; ++kl) {
                int Pl  = (hf*12 + kl)*8 + ksel*2;
                int ktl = Pl >> 6;
                int cp  = Pl & 63;
                U2H wa;
                uint4 q = wq[kl >> 1];
                if (kl & 1) { wa.u.x = q.z; wa.u.y = q.w; }
                else        { wa.u.x = q.x; wa.u.y = q.y; }
                U2H bfr;
                bfr.u = *(const uint2*)&tile[(pxt*16 + row + ktl)*68 + cp];
                acc = __builtin_amdgcn_mfma_f32_16x16x16f16(wa.h, bfr.h, acc, 0, 0, 0);
            }
        }
    }

    int gx = xq*32 + pxt*16 + row;
#pragma unroll
    for (int rI = 0; rI < 4; ++rI) {
        int och = mt*16 + ksel*4 + rI;
        if (och < 27) {
            float v = acc[rI] + ob[och];
            if (och >= 18) v = 1.f / (1.f + __expf(-v));   // mask sigmoid
            om[((b*27 + och) << 14) + (y << 7) + gx] = v;
        }
    }
}

// ---------------- K2: deformable conv (R19 body) — now writes aligned as
// PACKED F16 pairs: u32 at [b][c][y][xq*16+row] = (px=xq*32+row, px+16).
// Halves the 67 MB f32 intermediate write (and k4's read). Stats partials
// still computed from f32 accs (pre-rounding).
__global__ __launch_bounds__(256) void k2_deform(
    const unsigned* __restrict__ f13t, const unsigned* __restrict__ wmf,
    const float* __restrict__ om, unsigned* __restrict__ alignedh,
    float* __restrict__ part)
{
    extern __shared__ unsigned lds[];
    unsigned* pl_a = lds;            // [9][32] addr|dx<<14|dy<<15
    unsigned* pl_w = lds + 288;      // [9][32] x uint2 {half2(w00,w01), half2(w10,w11)}
    unsigned* sl   = lds + 864;      // [32 px][100] permuted half2 samples

    int blk0 = blockIdx.x;
    int blk  = ((blk0 & 7) << 8) | (blk0 >> 3);   // bijective (2048 % 8 == 0)
    int xq = blk & 3;
    int y  = (blk >> 2) & 127;
    int b  = blk >> 9;

    int tid  = threadIdx.x;
    int lane = tid & 63;
    int wv   = tid >> 6;
    int row  = lane & 15;
    int ksel = lane >> 4;
    int cg   = tid & 7;          // phase-A channel group (8 ch = 4 pairs)
    int grp  = tid >> 3;         // phase-A item group 0..31
    int pwb  = ((cg >> 2) << 4) | ((cg & 1) << 3) | (((cg >> 1) & 1) << 1);

    const float* omb = om + ((b*27) << 14) + (y << 7);
    const unsigned* ftb = f13t + (((size_t)b) << 20);

    // ---- param pre-phase: 288 items (k, px)
    for (int i = tid; i < 288; i += 256) {
        int k = i >> 5, lpx = i & 31;
        int gxp = xq*32 + lpx;
        float off0 = omb[((2*k)   << 14) + gxp];
        float off1 = omb[((2*k+1) << 14) + gxp];
        float mk   = omb[((18+k)  << 14) + gxp];   // sigmoided in K1

        float pyf = (float)y   + (float)(k/3) - 1.f + off0;
        float pxg = (float)gxp + (float)(k%3) - 1.f + off1;
        float fy = floorf(pyf), fx = floorf(pxg);
        int y0 = (int)fy, x0 = (int)fx;
        float wy = pyf - fy, wx = pxg - fx;
        float oy = 1.f - wy, ox = 1.f - wx;
        bool yv0 = (unsigned)y0     < (unsigned)HH;
        bool yv1 = (unsigned)(y0+1) < (unsigned)HH;
        bool xv0 = (unsigned)x0     < (unsigned)WW;
        bool xv1 = (unsigned)(x0+1) < (unsigned)WW;
        int y0c = min(max(y0, 0), 127);
        int x0c = min(max(x0, 0), 127);
        int dy = min(max(y0+1, 0), 127) - y0c;   // 0 or 1
        int dx = min(max(x0+1, 0), 127) - x0c;   // 0 or 1
        unsigned a = (unsigned)((y0c << 7) + x0c) | ((unsigned)dx << 14) | ((unsigned)dy << 15);
        float w00 = (yv0 && xv0) ? oy*ox*mk : 0.f;
        float w01 = (yv0 && xv1) ? oy*wx*mk : 0.f;
        float w10 = (yv1 && xv0) ? wy*ox*mk : 0.f;
        float w11 = (yv1 && xv1) ? wy*wx*mk : 0.f;
        pl_a[i] = a;
        pl_w[i*2]     = pk2u(w00, w01);
        pl_w[i*2 + 1] = pk2u(w10, w11);
    }
    __syncthreads();

    f32x4 acc0 = {0.f, 0.f, 0.f, 0.f};
    f32x4 acc1 = {0.f, 0.f, 0.f, 0.f};

    const unsigned* wbase = wmf + (wv*64 + lane)*72;

#pragma unroll 1
    for (int th = 0; th < 3; ++th) {
        uint4 wq[6];
#pragma unroll
        for (int m = 0; m < 6; ++m)
            wq[m] = *(const uint4*)&wbase[th*24 + m*4];

        // phase A: 96 items (ktl,px); 8-lane group = one item
#pragma unroll
        for (int it = 0; it < 3; ++it) {
            int item = it*32 + grp;            // 0..95
            int ktl  = item >> 5;              // 0..2
            int px   = item & 31;
            int k    = th*3 + ktl;
            int pidx = k*32 + px;
            unsigned a = pl_a[pidx];
            uint2 wpk = *(const uint2*)&pl_w[pidx*2];
            int i00 = (int)(a & 0x3FFFu);
            int dx  = (int)((a >> 14) & 1u);
            int i10 = i00 + (((int)(a >> 15) & 1) << 7);
            h2 hw01 = u2h(wpk.x);
            h2 hw23 = u2h(wpk.y);
            h2 w00d = {hw01.x, hw01.x}, w01d = {hw01.y, hw01.y};
            h2 w10d = {hw23.x, hw23.x}, w11d = {hw23.y, hw23.y};

            uint4 t00 = *(const uint4*)&ftb[(size_t)(i00     )*64 + 4*cg];
            uint4 t01 = *(const uint4*)&ftb[(size_t)(i00 + dx)*64 + 4*cg];
            uint4 t10 = *(const uint4*)&ftb[(size_t)(i10     )*64 + 4*cg];
            uint4 t11 = *(const uint4*)&ftb[(size_t)(i10 + dx)*64 + 4*cg];

            h2 v0 = u2h(t00.x)*w00d + u2h(t01.x)*w01d + u2h(t10.x)*w10d + u2h(t11.x)*w11d;
            h2 v1 = u2h(t00.y)*w00d + u2h(t01.y)*w01d + u2h(t10.y)*w10d + u2h(t11.y)*w11d;
            h2 v2 = u2h(t00.z)*w00d + u2h(t01.z)*w01d + u2h(t10.z)*w10d + u2h(t11.z)*w11d;
            h2 v3 = u2h(t00.w)*w00d + u2h(t01.w)*w01d + u2h(t10.w)*w10d + u2h(t11.w)*w11d;

            int bs = px*100 + ktl*32 + pwb;
            *(uint2*)&sl[bs]     = make_uint2(h2u(v0), h2u(v1));
            *(uint2*)&sl[bs + 4] = make_uint2(h2u(v2), h2u(v3));
        }
        __syncthreads();

        // phase B: 6 double-K-blocks x 2 px-tiles, ds_read_b128
        const unsigned* b0p = &sl[(row     )*100 + ksel*4];
        const unsigned* b1p = &sl[(16+row  )*100 + ksel*4];
#pragma unroll
        for (int m = 0; m < 6; ++m) {
            uint4 bv0 = *(const uint4*)&b0p[m*16];
            uint4 bv1 = *(const uint4*)&b1p[m*16];
            U2H waA, waB, s0a, s0b, s1a, s1b;
            waA.u.x = wq[m].x; waA.u.y = wq[m].y;
            waB.u.x = wq[m].z; waB.u.y = wq[m].w;
            s0a.u.x = bv0.x; s0a.u.y = bv0.y;
            s0b.u.x = bv0.z; s0b.u.y = bv0.w;
            s1a.u.x = bv1.x; s1a.u.y = bv1.y;
            s1b.u.x = bv1.z; s1b.u.y = bv1.w;
            acc0 = __builtin_amdgcn_mfma_f32_16x16x16f16(waA.h, s0a.h, acc0, 0, 0, 0);
            acc0 = __builtin_amdgcn_mfma_f32_16x16x16f16(waB.h, s0b.h, acc0, 0, 0, 0);
            acc1 = __builtin_amdgcn_mfma_f32_16x16x16f16(waA.h, s1a.h, acc1, 0, 0, 0);
            acc1 = __builtin_amdgcn_mfma_f32_16x16x16f16(waB.h, s1b.h, acc1, 0, 0, 0);
        }
        __syncthreads();
    }

    // write aligned (packed f16: px and px+16) + per-block stats partials
    float* sred = (float*)lds;   // reuse (safe: past last barrier, sl dead)
    int obase = ((b*CC) << 13) + (y << 6) + (xq << 4);
#pragma unroll
    for (int rI = 0; rI < 4; ++rI) {
        int och = wv*16 + ksel*4 + rI;
        float v0 = acc0[rI], v1 = acc1[rI];
        alignedh[obase + (och << 13) + row] = pk2u(v0, v1);
        float s  = v0 + v1;
        float sq = v0*v0 + v1*v1;
#pragma unroll
        for (int off = 1; off < 16; off <<= 1) {
            s  += __shfl_xor(s,  off, 64);
            sq += __shfl_xor(sq, off, 64);
        }
        if (row == 0) { sred[och] = s; sred[64 + och] = sq; }
    }
    __syncthreads();
    for (int i = tid; i < 128; i += 256)
        part[(size_t)blk*128 + i] = sred[i];
}

// ---------------- K3b: reduce 2048 per-block partials -> stats[128]
__global__ __launch_bounds__(256) void k3b_reduce(
    const float* __restrict__ part, float* __restrict__ stats)
{
    int i = blockIdx.x;           // 0..127
    int tid = threadIdx.x;
    float s = 0.f;
    for (int j = tid; j < 2048; j += 256) s += part[(size_t)j*128 + i];
    for (int off = 32; off > 0; off >>= 1) s += __shfl_down(s, off, 64);
    __shared__ float rs[4];
    int w = tid >> 6;
    if ((tid & 63) == 0) rs[w] = s;
    __syncthreads();
    if (tid == 0) stats[i] = rs[0] + rs[1] + rs[2] + rs[3];
}

// ---------------- K4: normalize + affine, f16-packed input -> f32 out.
// u32 index u = ((b*64+c)<<13) + (y<<6) + (xq<<4) + lx; holds (x, x+16) with
// x = xq*32 + lx. One thread = one uint4 (4 u32 = 8 values, 2x float4 out).
__global__ __launch_bounds__(256) void k4_norm(
    const unsigned* __restrict__ alignedh, const float* __restrict__ stats,
    const float* __restrict__ gamma, const float* __restrict__ beta,
    float* __restrict__ out)
{
    const float invN = 1.f / 65536.f;
    int i4 = blockIdx.x*256 + threadIdx.x;     // 0..524287
    int u  = i4 << 2;
    int c  = (u >> 13) & 63;
    int lx = u & 15;
    int xq = (u >> 4) & 3;
    int y  = (u >> 6) & 127;
    int bc = u >> 13;                          // b*64 + c

    float mean = stats[c] * invN;
    float var  = stats[64 + c] * invN - mean*mean;
    float sc = gamma[c] * rsqrtf(var + 1e-5f);
    float sh = beta[c] - mean*sc;

    uint4 v = *(const uint4*)&alignedh[u];
    h2 p0 = u2h(v.x), p1 = u2h(v.y), p2 = u2h(v.z), p3 = u2h(v.w);
    float4 lo = make_float4((float)p0.x*sc + sh, (float)p1.x*sc + sh,
                            (float)p2.x*sc + sh, (float)p3.x*sc + sh);
    float4 hi = make_float4((float)p0.y*sc + sh, (float)p1.y*sc + sh,
                            (float)p2.y*sc + sh, (float)p3.y*sc + sh);
    int ob = (bc << 14) + (y << 7) + xq*32 + lx;
    *(float4*)&out[ob]      = lo;
    *(float4*)&out[ob + 16] = hi;
}

extern "C" void kernel_launch(void* const* d_in, const int* in_sizes, int n_in,
                              void* d_out, int out_size, void* d_ws, size_t ws_size,
                              hipStream_t stream)
{
    const float* f1    = (const float*)d_in[0];
    const float* f3    = (const float*)d_in[1];
    const float* ow    = (const float*)d_in[2];
    const float* ob    = (const float*)d_in[3];
    const float* mw    = (const float*)d_in[4];
    const float* gamma = (const float*)d_in[5];
    const float* beta  = (const float*)d_in[6];
    float* out = (float*)d_out;

    float* om     = (float*)d_ws;                 // [4][27][128][128] = 7,077,888 B
    float* stats  = om + 4*27*HWP;                // [128] floats (512 reserved)
    unsigned* wmf = (unsigned*)(stats + 512);     // 18432 u32
    unsigned* wof = wmf + 18432;                  // 18432 u32
    unsigned* f13t = wof + 18432;                 // [4][128][128][64] u32 = 16 MB
    float* part   = (float*)(f13t + 4*HWP*64);    // [2048][128] = 1 MB
    unsigned* alignedh = (unsigned*)(part + 2048*128);  // [4][64][128][64] u32 = 33.5 MB

    const int lds2 = (864 + 32*100) * 4;          // 16,256 B
    (void)hipFuncSetAttribute((const void*)k2_deform,
        hipFuncAttributeMaxDynamicSharedMemorySize, lds2);

    hipLaunchKernelGGL(kTm, dim3(656), dim3(256), 0, stream,
                       f1, f3, ow, mw, f13t, wmf, wof);
    hipLaunchKernelGGL(k1_offset_conv, dim3(2048), dim3(256), 0, stream,
                       f13t, wof, ob, om);
    hipLaunchKernelGGL(k2_deform, dim3(2048), dim3(256), lds2, stream,
                       f13t, wmf, om, alignedh, part);
    hipLaunchKernelGGL(k3b_reduce, dim3(128), dim3(256), 0, stream, part, stats);
    hipLaunchKernelGGL(k4_norm, dim3(2048), dim3(256), 0, stream,
                       alignedh, stats, gamma, beta, out);
}

// Round 21
// 69.986 us; speedup vs baseline: 3.8789x; 1.1199x over previous
//
#include <hip/hip_runtime.h>
#include <math.h>

#define BB 4
#define CC 64
#define HH 128
#define WW 128
#define HWP 16384

typedef _Float16 h2 __attribute__((ext_vector_type(2)));
typedef _Float16 h4 __attribute__((ext_vector_type(4)));
typedef __fp16  p2 __attribute__((ext_vector_type(2)));   // cvt_pkrtz's return type
typedef float f32x4 __attribute__((ext_vector_type(4)));
union HU { unsigned u; h2 h; p2 p; };
union U2H { uint2 u; h4 h; };
static __device__ __forceinline__ h2 u2h(unsigned x){ HU v; v.u = x; return v.h; }
static __device__ __forceinline__ unsigned h2u(h2 x){ HU v; v.h = x; return v.u; }
static __device__ __forceinline__ unsigned pk2u(float a, float b){
    HU v; v.p = __builtin_amdgcn_cvt_pkrtz(a, b); return v.u;
}

// ---------------- kTm: merged kT (blocks 0..511) + k0 weight-pack (512..655).
__global__ __launch_bounds__(256) void kTm(
    const float* __restrict__ f1, const float* __restrict__ f3,
    const float* __restrict__ ow, const float* __restrict__ mw,
    unsigned* __restrict__ f13t, unsigned* __restrict__ wmf,
    unsigned* __restrict__ wof)
{
    __shared__ float lt[64*129];
    int t = threadIdx.x;
    if (blockIdx.x < 512) {
        int b = blockIdx.x >> 7, y = blockIdx.x & 127;
        unsigned* dst = f13t + ((size_t)((b << 14) + (y << 7)))*64;
        for (int half = 0; half < 2; ++half) {
            const float* src = (half == 0 ? f1 : f3) + (((size_t)b*64) << 14) + (y << 7);
#pragma unroll 4
            for (int i = 0; i < 32; ++i) {
                int idx = i*256 + t; int c = idx >> 7, x = idx & 127;
                lt[c*129 + x] = src[(c << 14) + x];
            }
            __syncthreads();
#pragma unroll 4
            for (int i = 0; i < 16; ++i) {
                int idx = i*256 + t; int x = idx >> 5, cp = idx & 31;
                dst[x*64 + half*32 + cp] = pk2u(lt[(2*cp)*129 + x], lt[(2*cp+1)*129 + x]);
            }
            __syncthreads();
        }
        return;
    }
    int i = (blockIdx.x - 512)*256 + t;
    if (i < 18432) {                           // wmf: 4*64*36*2
        int j   = i & 1;
        int t2  = i >> 1;
        int kb  = t2 % 36;
        int rl  = t2 / 36;
        int l   = rl & 63;
        int r   = rl >> 6;
        int row = l & 15, ksel = l >> 4;
        int och = r*16 + row;
        int P   = kb*8 + ksel*2 + j;           // 0..287
        int kt  = P >> 5;
        int cp  = P & 31;
        float lo = mw[och*576 + (2*cp    )*9 + kt];
        float hi = mw[och*576 + (2*cp + 1)*9 + kt];
        wmf[i] = pk2u(lo, hi);
    } else if (i < 36864) {                    // wof: 2*64*72*2
        int idx = i - 18432;
        int j   = idx & 1;
        int t2  = idx >> 1;
        int kb  = t2 % 72;
        int rl  = t2 / 72;
        int l   = rl & 63;
        int mt  = rl >> 6;
        int row = l & 15, ksel = l >> 4;
        int och = mt*16 + row;
        int P   = kb*8 + ksel*2 + j;           // 0..575
        int kt  = P >> 6;                      // tap 0..8
        int cp  = P & 63;                      // concat pair
        unsigned v = 0;
        if (och < 27) {
            float lo = ow[(och*128 + 2*cp    )*9 + kt];
            float hi = ow[(och*128 + 2*cp + 1)*9 + kt];
            v = pk2u(lo, hi);
        }
        wof[idx] = v;
    }
}

// ---------------- K1: offset conv via MFMA, y-PAIR blocks (R21).
// grid 1024 = (b, y-pair, xq); stage 4 row-slabs [34][68] ONCE (36.9 KB LDS,
// single barrier), then waves = (mt, row-of-pair) compute 16 och x 32 px.
// Slab staging per output row: 2 (was 3); stage barriers per 2 rows: 1 (was 6).
__global__ __launch_bounds__(256) void k1_offset_conv(
    const unsigned* __restrict__ f13t, const unsigned* __restrict__ wof,
    const float* __restrict__ ob, float* __restrict__ om)
{
    extern __shared__ unsigned tile[];   // [4 slabs][34][68] = 36,992 B

    int blk0 = blockIdx.x;
    int blk  = ((blk0 & 7) << 7) | (blk0 >> 3);   // bijective (1024 % 8 == 0)
    int xq = blk & 3;
    int yp = (blk >> 2) & 63;
    int b  = blk >> 8;
    int y0r = yp << 1;

    int tid  = threadIdx.x;
    int lane = tid & 63;
    int wv   = tid >> 6;
    int mt   = wv >> 1;          // M-tile (out-ch 16*mt..)
    int ys   = wv & 1;           // row of pair
    int row  = lane & 15;
    int ksel = lane >> 4;

    // stage 4 slabs: rows y0r-1 .. y0r+2
#pragma unroll 1
    for (int s = 0; s < 4; ++s) {
        int yy = y0r + s - 1;
        bool yok = (unsigned)yy < (unsigned)HH;
        unsigned* ts = tile + s*2312;
        for (int i = tid; i < 544; i += 256) {
            int px34 = i >> 4, q = i & 15;
            int gxp = xq*32 - 1 + px34;
            uint4 v = make_uint4(0u, 0u, 0u, 0u);
            if (yok && (unsigned)gxp < (unsigned)WW)
                v = *(const uint4*)&f13t[(((size_t)(b*128 + yy))*128 + gxp)*64 + q*4];
            *(uint4*)&ts[px34*68 + q*4] = v;
        }
    }
    __syncthreads();

    f32x4 acc0 = {0.f, 0.f, 0.f, 0.f};
    f32x4 acc1 = {0.f, 0.f, 0.f, 0.f};
    const unsigned* wbase = wof + (size_t)(mt*64 + lane)*144;

#pragma unroll 1
    for (int dy = 0; dy < 3; ++dy) {
        const unsigned* ts = tile + (ys + dy)*2312;
#pragma unroll
        for (int hf = 0; hf < 2; ++hf) {
            uint4 wq[6];
#pragma unroll
            for (int m = 0; m < 6; ++m)
                wq[m] = *(const uint4*)&wbase[dy*48 + hf*24 + m*4];
#pragma unroll
            for (int kl = 0; kl < 12; ++kl) {
                int Pl  = (hf*12 + kl)*8 + ksel*2;
                int ktl = Pl >> 6;
                int cp  = Pl & 63;
                U2H wa;
                uint4 q = wq[kl >> 1];
                if (kl & 1) { wa.u.x = q.z; wa.u.y = q.w; }
                else        { wa.u.x = q.x; wa.u.y = q.y; }
                U2H b0, b1;
                b0.u = *(const uint2*)&ts[(row + ktl)*68 + cp];
                b1.u = *(const uint2*)&ts[(16 + row + ktl)*68 + cp];
                acc0 = __builtin_amdgcn_mfma_f32_16x16x16f16(wa.h, b0.h, acc0, 0, 0, 0);
                acc1 = __builtin_amdgcn_mfma_f32_16x16x16f16(wa.h, b1.h, acc1, 0, 0, 0);
            }
        }
    }

    int y  = y0r + ys;
    int gx0 = xq*32 + row;
#pragma unroll
    for (int rI = 0; rI < 4; ++rI) {
        int och = mt*16 + ksel*4 + rI;
        if (och < 27) {
            float v0 = acc0[rI] + ob[och];
            float v1 = acc1[rI] + ob[och];
            if (och >= 18) {
                v0 = 1.f / (1.f + __expf(-v0));   // mask sigmoid
                v1 = 1.f / (1.f + __expf(-v1));
            }
            int base = ((b*27 + och) << 14) + (y << 7) + gx0;
            om[base]      = v0;
            om[base + 16] = v1;
        }
    }
}

// ---------------- K2: deformable conv (R20 body, unchanged).
__global__ __launch_bounds__(256) void k2_deform(
    const unsigned* __restrict__ f13t, const unsigned* __restrict__ wmf,
    const float* __restrict__ om, unsigned* __restrict__ alignedh,
    float* __restrict__ part)
{
    extern __shared__ unsigned lds[];
    unsigned* pl_a = lds;            // [9][32] addr|dx<<14|dy<<15
    unsigned* pl_w = lds + 288;      // [9][32] x uint2 {half2(w00,w01), half2(w10,w11)}
    unsigned* sl   = lds + 864;      // [32 px][100] permuted half2 samples

    int blk0 = blockIdx.x;
    int blk  = ((blk0 & 7) << 8) | (blk0 >> 3);   // bijective (2048 % 8 == 0)
    int xq = blk & 3;
    int y  = (blk >> 2) & 127;
    int b  = blk >> 9;

    int tid  = threadIdx.x;
    int lane = tid & 63;
    int wv   = tid >> 6;
    int row  = lane & 15;
    int ksel = lane >> 4;
    int cg   = tid & 7;          // phase-A channel group (8 ch = 4 pairs)
    int grp  = tid >> 3;         // phase-A item group 0..31
    int pwb  = ((cg >> 2) << 4) | ((cg & 1) << 3) | (((cg >> 1) & 1) << 1);

    const float* omb = om + ((b*27) << 14) + (y << 7);
    const unsigned* ftb = f13t + (((size_t)b) << 20);

    // ---- param pre-phase: 288 items (k, px)
    for (int i = tid; i < 288; i += 256) {
        int k = i >> 5, lpx = i & 31;
        int gxp = xq*32 + lpx;
        float off0 = omb[((2*k)   << 14) + gxp];
        float off1 = omb[((2*k+1) << 14) + gxp];
        float mk   = omb[((18+k)  << 14) + gxp];   // sigmoided in K1

        float pyf = (float)y   + (float)(k/3) - 1.f + off0;
        float pxg = (float)gxp + (float)(k%3) - 1.f + off1;
        float fy = floorf(pyf), fx = floorf(pxg);
        int y0 = (int)fy, x0 = (int)fx;
        float wy = pyf - fy, wx = pxg - fx;
        float oy = 1.f - wy, ox = 1.f - wx;
        bool yv0 = (unsigned)y0     < (unsigned)HH;
        bool yv1 = (unsigned)(y0+1) < (unsigned)HH;
        bool xv0 = (unsigned)x0     < (unsigned)WW;
        bool xv1 = (unsigned)(x0+1) < (unsigned)WW;
        int y0c = min(max(y0, 0), 127);
        int x0c = min(max(x0, 0), 127);
        int dy = min(max(y0+1, 0), 127) - y0c;   // 0 or 1
        int dx = min(max(x0+1, 0), 127) - x0c;   // 0 or 1
        unsigned a = (unsigned)((y0c << 7) + x0c) | ((unsigned)dx << 14) | ((unsigned)dy << 15);
        float w00 = (yv0 && xv0) ? oy*ox*mk : 0.f;
        float w01 = (yv0 && xv1) ? oy*wx*mk : 0.f;
        float w10 = (yv1 && xv0) ? wy*ox*mk : 0.f;
        float w11 = (yv1 && xv1) ? wy*wx*mk : 0.f;
        pl_a[i] = a;
        pl_w[i*2]     = pk2u(w00, w01);
        pl_w[i*2 + 1] = pk2u(w10, w11);
    }
    __syncthreads();

    f32x4 acc0 = {0.f, 0.f, 0.f, 0.f};
    f32x4 acc1 = {0.f, 0.f, 0.f, 0.f};

    const unsigned* wbase = wmf + (wv*64 + lane)*72;

#pragma unroll 1
    for (int th = 0; th < 3; ++th) {
        uint4 wq[6];
#pragma unroll
        for (int m = 0; m < 6; ++m)
            wq[m] = *(const uint4*)&wbase[th*24 + m*4];

        // phase A: 96 items (ktl,px); 8-lane group = one item
#pragma unroll
        for (int it = 0; it < 3; ++it) {
            int item = it*32 + grp;            // 0..95
            int ktl  = item >> 5;              // 0..2
            int px   = item & 31;
            int k    = th*3 + ktl;
            int pidx = k*32 + px;
            unsigned a = pl_a[pidx];
            uint2 wpk = *(const uint2*)&pl_w[pidx*2];
            int i00 = (int)(a & 0x3FFFu);
            int dx  = (int)((a >> 14) & 1u);
            int i10 = i00 + (((int)(a >> 15) & 1) << 7);
            h2 hw01 = u2h(wpk.x);
            h2 hw23 = u2h(wpk.y);
            h2 w00d = {hw01.x, hw01.x}, w01d = {hw01.y, hw01.y};
            h2 w10d = {hw23.x, hw23.x}, w11d = {hw23.y, hw23.y};

            uint4 t00 = *(const uint4*)&ftb[(size_t)(i00     )*64 + 4*cg];
            uint4 t01 = *(const uint4*)&ftb[(size_t)(i00 + dx)*64 + 4*cg];
            uint4 t10 = *(const uint4*)&ftb[(size_t)(i10     )*64 + 4*cg];
            uint4 t11 = *(const uint4*)&ftb[(size_t)(i10 + dx)*64 + 4*cg];

            h2 v0 = u2h(t00.x)*w00d + u2h(t01.x)*w01d + u2h(t10.x)*w10d + u2h(t11.x)*w11d;
            h2 v1 = u2h(t00.y)*w00d + u2h(t01.y)*w01d + u2h(t10.y)*w10d + u2h(t11.y)*w11d;
            h2 v2 = u2h(t00.z)*w00d + u2h(t01.z)*w01d + u2h(t10.z)*w10d + u2h(t11.z)*w11d;
            h2 v3 = u2h(t00.w)*w00d + u2h(t01.w)*w01d + u2h(t10.w)*w10d + u2h(t11.w)*w11d;

            int bs = px*100 + ktl*32 + pwb;
            *(uint2*)&sl[bs]     = make_uint2(h2u(v0), h2u(v1));
            *(uint2*)&sl[bs + 4] = make_uint2(h2u(v2), h2u(v3));
        }
        __syncthreads();

        // phase B: 6 double-K-blocks x 2 px-tiles, ds_read_b128
        const unsigned* b0p = &sl[(row     )*100 + ksel*4];
        const unsigned* b1p = &sl[(16+row  )*100 + ksel*4];
#pragma unroll
        for (int m = 0; m < 6; ++m) {
            uint4 bv0 = *(const uint4*)&b0p[m*16];
            uint4 bv1 = *(const uint4*)&b1p[m*16];
            U2H waA, waB, s0a, s0b, s1a, s1b;
            waA.u.x = wq[m].x; waA.u.y = wq[m].y;
            waB.u.x = wq[m].z; waB.u.y = wq[m].w;
            s0a.u.x = bv0.x; s0a.u.y = bv0.y;
            s0b.u.x = bv0.z; s0b.u.y = bv0.w;
            s1a.u.x = bv1.x; s1a.u.y = bv1.y;
            s1b.u.x = bv1.z; s1b.u.y = bv1.w;
            acc0 = __builtin_amdgcn_mfma_f32_16x16x16f16(waA.h, s0a.h, acc0, 0, 0, 0);
            acc0 = __builtin_amdgcn_mfma_f32_16x16x16f16(waB.h, s0b.h, acc0, 0, 0, 0);
            acc1 = __builtin_amdgcn_mfma_f32_16x16x16f16(waA.h, s1a.h, acc1, 0, 0, 0);
            acc1 = __builtin_amdgcn_mfma_f32_16x16x16f16(waB.h, s1b.h, acc1, 0, 0, 0);
        }
        __syncthreads();
    }

    // write aligned (packed f16: px and px+16) + per-block stats partials
    float* sred = (float*)lds;   // reuse (safe: past last barrier, sl dead)
    int obase = ((b*CC) << 13) + (y << 6) + (xq << 4);
#pragma unroll
    for (int rI = 0; rI < 4; ++rI) {
        int och = wv*16 + ksel*4 + rI;
        float v0 = acc0[rI], v1 = acc1[rI];
        alignedh[obase + (och << 13) + row] = pk2u(v0, v1);
        float s  = v0 + v1;
        float sq = v0*v0 + v1*v1;
#pragma unroll
        for (int off = 1; off < 16; off <<= 1) {
            s  += __shfl_xor(s,  off, 64);
            sq += __shfl_xor(sq, off, 64);
        }
        if (row == 0) { sred[och] = s; sred[64 + och] = sq; }
    }
    __syncthreads();
    for (int i = tid; i < 128; i += 256)
        part[(size_t)blk*128 + i] = sred[i];
}

// ---------------- K3b: reduce 2048 per-block partials -> stats[128]
__global__ __launch_bounds__(256) void k3b_reduce(
    const float* __restrict__ part, float* __restrict__ stats)
{
    int i = blockIdx.x;           // 0..127
    int tid = threadIdx.x;
    float s = 0.f;
    for (int j = tid; j < 2048; j += 256) s += part[(size_t)j*128 + i];
    for (int off = 32; off > 0; off >>= 1) s += __shfl_down(s, off, 64);
    __shared__ float rs[4];
    int w = tid >> 6;
    if ((tid & 63) == 0) rs[w] = s;
    __syncthreads();
    if (tid == 0) stats[i] = rs[0] + rs[1] + rs[2] + rs[3];
}

// ---------------- K4: normalize + affine, f16-packed input -> f32 out.
__global__ __launch_bounds__(256) void k4_norm(
    const unsigned* __restrict__ alignedh, const float* __restrict__ stats,
    const float* __restrict__ gamma, const float* __restrict__ beta,
    float* __restrict__ out)
{
    const float invN = 1.f / 65536.f;
    int i4 = blockIdx.x*256 + threadIdx.x;     // 0..524287
    int u  = i4 << 2;
    int c  = (u >> 13) & 63;
    int lx = u & 15;
    int xq = (u >> 4) & 3;
    int y  = (u >> 6) & 127;
    int bc = u >> 13;                          // b*64 + c

    float mean = stats[c] * invN;
    float var  = stats[64 + c] * invN - mean*mean;
    float sc = gamma[c] * rsqrtf(var + 1e-5f);
    float sh = beta[c] - mean*sc;

    uint4 v = *(const uint4*)&alignedh[u];
    h2 p0 = u2h(v.x), p1 = u2h(v.y), p2 = u2h(v.z), p3 = u2h(v.w);
    float4 lo = make_float4((float)p0.x*sc + sh, (float)p1.x*sc + sh,
                            (float)p2.x*sc + sh, (float)p3.x*sc + sh);
    float4 hi = make_float4((float)p0.y*sc + sh, (float)p1.y*sc + sh,
                            (float)p2.y*sc + sh, (float)p3.y*sc + sh);
    int ob = (bc << 14) + (y << 7) + xq*32 + lx;
    *(float4*)&out[ob]      = lo;
    *(float4*)&out[ob + 16] = hi;
}

extern "C" void kernel_launch(void* const* d_in, const int* in_sizes, int n_in,
                              void* d_out, int out_size, void* d_ws, size_t ws_size,
                              hipStream_t stream)
{
    const float* f1    = (const float*)d_in[0];
    const float* f3    = (const float*)d_in[1];
    const float* ow    = (const float*)d_in[2];
    const float* ob    = (const float*)d_in[3];
    const float* mw    = (const float*)d_in[4];
    const float* gamma = (const float*)d_in[5];
    const float* beta  = (const float*)d_in[6];
    float* out = (float*)d_out;

    float* om     = (float*)d_ws;                 // [4][27][128][128] = 7,077,888 B
    float* stats  = om + 4*27*HWP;                // [128] floats (512 reserved)
    unsigned* wmf = (unsigned*)(stats + 512);     // 18432 u32
    unsigned* wof = wmf + 18432;                  // 18432 u32
    unsigned* f13t = wof + 18432;                 // [4][128][128][64] u32 = 16 MB
    float* part   = (float*)(f13t + 4*HWP*64);    // [2048][128] = 1 MB
    unsigned* alignedh = (unsigned*)(part + 2048*128);  // [4][64][128][64] u32 = 33.5 MB

    const int lds1 = 4*2312*4;                    // 36,992 B (k1)
    const int lds2 = (864 + 32*100) * 4;          // 16,256 B (k2)
    (void)hipFuncSetAttribute((const void*)k1_offset_conv,
        hipFuncAttributeMaxDynamicSharedMemorySize, lds1);
    (void)hipFuncSetAttribute((const void*)k2_deform,
        hipFuncAttributeMaxDynamicSharedMemorySize, lds2);

    hipLaunchKernelGGL(kTm, dim3(656), dim3(256), 0, stream,
                       f1, f3, ow, mw, f13t, wmf, wof);
    hipLaunchKernelGGL(k1_offset_conv, dim3(1024), dim3(256), lds1, stream,
                       f13t, wof, ob, om);
    hipLaunchKernelGGL(k2_deform, dim3(2048), dim3(256), lds2, stream,
                       f13t, wmf, om, alignedh, part);
    hipLaunchKernelGGL(k3b_reduce, dim3(128), dim3(256), 0, stream, part, stats);
    hipLaunchKernelGGL(k4_norm, dim3(2048), dim3(256), 0, stream,
                       alignedh, stats, gamma, beta, out);
}

// Round 22
// 63.176 us; speedup vs baseline: 4.2970x; 1.1078x over previous
//
#include <hip/hip_runtime.h>
#include <math.h>

#define BB 4
#define CC 64
#define HH 128
#define WW 128
#define HWP 16384

typedef _Float16 h2 __attribute__((ext_vector_type(2)));
typedef _Float16 h4 __attribute__((ext_vector_type(4)));
typedef __fp16  p2 __attribute__((ext_vector_type(2)));   // cvt_pkrtz's return type
typedef float f32x4 __attribute__((ext_vector_type(4)));
union HU { unsigned u; h2 h; p2 p; };
union U2H { uint2 u; h4 h; };
static __device__ __forceinline__ h2 u2h(unsigned x){ HU v; v.u = x; return v.h; }
static __device__ __forceinline__ unsigned h2u(h2 x){ HU v; v.h = x; return v.u; }
static __device__ __forceinline__ unsigned pk2u(float a, float b){
    HU v; v.p = __builtin_amdgcn_cvt_pkrtz(a, b); return v.u;
}

// ---------------- kTm: merged kT (blocks 0..511) + k0 weight-pack (512..655).
__global__ __launch_bounds__(256) void kTm(
    const float* __restrict__ f1, const float* __restrict__ f3,
    const float* __restrict__ ow, const float* __restrict__ mw,
    unsigned* __restrict__ f13t, unsigned* __restrict__ wmf,
    unsigned* __restrict__ wof)
{
    __shared__ float lt[64*129];
    int t = threadIdx.x;
    if (blockIdx.x < 512) {
        int b = blockIdx.x >> 7, y = blockIdx.x & 127;
        unsigned* dst = f13t + ((size_t)((b << 14) + (y << 7)))*64;
        for (int half = 0; half < 2; ++half) {
            const float* src = (half == 0 ? f1 : f3) + (((size_t)b*64) << 14) + (y << 7);
#pragma unroll 4
            for (int i = 0; i < 32; ++i) {
                int idx = i*256 + t; int c = idx >> 7, x = idx & 127;
                lt[c*129 + x] = src[(c << 14) + x];
            }
            __syncthreads();
#pragma unroll 4
            for (int i = 0; i < 16; ++i) {
                int idx = i*256 + t; int x = idx >> 5, cp = idx & 31;
                dst[x*64 + half*32 + cp] = pk2u(lt[(2*cp)*129 + x], lt[(2*cp+1)*129 + x]);
            }
            __syncthreads();
        }
        return;
    }
    int i = (blockIdx.x - 512)*256 + t;
    if (i < 18432) {                           // wmf: 4*64*36*2
        int j   = i & 1;
        int t2  = i >> 1;
        int kb  = t2 % 36;
        int rl  = t2 / 36;
        int l   = rl & 63;
        int r   = rl >> 6;
        int row = l & 15, ksel = l >> 4;
        int och = r*16 + row;
        int P   = kb*8 + ksel*2 + j;           // 0..287
        int kt  = P >> 5;
        int cp  = P & 31;
        float lo = mw[och*576 + (2*cp    )*9 + kt];
        float hi = mw[och*576 + (2*cp + 1)*9 + kt];
        wmf[i] = pk2u(lo, hi);
    } else if (i < 36864) {                    // wof: 2*64*72*2
        int idx = i - 18432;
        int j   = idx & 1;
        int t2  = idx >> 1;
        int kb  = t2 % 72;
        int rl  = t2 / 72;
        int l   = rl & 63;
        int mt  = rl >> 6;
        int row = l & 15, ksel = l >> 4;
        int och = mt*16 + row;
        int P   = kb*8 + ksel*2 + j;           // 0..575
        int kt  = P >> 6;                      // tap 0..8
        int cp  = P & 63;                      // concat pair
        unsigned v = 0;
        if (och < 27) {
            float lo = ow[(och*128 + 2*cp    )*9 + kt];
            float hi = ow[(och*128 + 2*cp + 1)*9 + kt];
            v = pk2u(lo, hi);
        }
        wof[idx] = v;
    }
}

// ---------------- K1: offset conv via MFMA, y-PAIR blocks (R21, unchanged).
__global__ __launch_bounds__(256) void k1_offset_conv(
    const unsigned* __restrict__ f13t, const unsigned* __restrict__ wof,
    const float* __restrict__ ob, float* __restrict__ om)
{
    extern __shared__ unsigned tile[];   // [4 slabs][34][68] = 36,992 B

    int blk0 = blockIdx.x;
    int blk  = ((blk0 & 7) << 7) | (blk0 >> 3);   // bijective (1024 % 8 == 0)
    int xq = blk & 3;
    int yp = (blk >> 2) & 63;
    int b  = blk >> 8;
    int y0r = yp << 1;

    int tid  = threadIdx.x;
    int lane = tid & 63;
    int wv   = tid >> 6;
    int mt   = wv >> 1;          // M-tile (out-ch 16*mt..)
    int ys   = wv & 1;           // row of pair
    int row  = lane & 15;
    int ksel = lane >> 4;

    // stage 4 slabs: rows y0r-1 .. y0r+2
#pragma unroll 1
    for (int s = 0; s < 4; ++s) {
        int yy = y0r + s - 1;
        bool yok = (unsigned)yy < (unsigned)HH;
        unsigned* ts = tile + s*2312;
        for (int i = tid; i < 544; i += 256) {
            int px34 = i >> 4, q = i & 15;
            int gxp = xq*32 - 1 + px34;
            uint4 v = make_uint4(0u, 0u, 0u, 0u);
            if (yok && (unsigned)gxp < (unsigned)WW)
                v = *(const uint4*)&f13t[(((size_t)(b*128 + yy))*128 + gxp)*64 + q*4];
            *(uint4*)&ts[px34*68 + q*4] = v;
        }
    }
    __syncthreads();

    f32x4 acc0 = {0.f, 0.f, 0.f, 0.f};
    f32x4 acc1 = {0.f, 0.f, 0.f, 0.f};
    const unsigned* wbase = wof + (size_t)(mt*64 + lane)*144;

#pragma unroll 1
    for (int dy = 0; dy < 3; ++dy) {
        const unsigned* ts = tile + (ys + dy)*2312;
#pragma unroll
        for (int hf = 0; hf < 2; ++hf) {
            uint4 wq[6];
#pragma unroll
            for (int m = 0; m < 6; ++m)
                wq[m] = *(const uint4*)&wbase[dy*48 + hf*24 + m*4];
#pragma unroll
            for (int kl = 0; kl < 12; ++kl) {
                int Pl  = (hf*12 + kl)*8 + ksel*2;
                int ktl = Pl >> 6;
                int cp  = Pl & 63;
                U2H wa;
                uint4 q = wq[kl >> 1];
                if (kl & 1) { wa.u.x = q.z; wa.u.y = q.w; }
                else        { wa.u.x = q.x; wa.u.y = q.y; }
                U2H b0, b1;
                b0.u = *(const uint2*)&ts[(row + ktl)*68 + cp];
                b1.u = *(const uint2*)&ts[(16 + row + ktl)*68 + cp];
                acc0 = __builtin_amdgcn_mfma_f32_16x16x16f16(wa.h, b0.h, acc0, 0, 0, 0);
                acc1 = __builtin_amdgcn_mfma_f32_16x16x16f16(wa.h, b1.h, acc1, 0, 0, 0);
            }
        }
    }

    int y  = y0r + ys;
    int gx0 = xq*32 + row;
#pragma unroll
    for (int rI = 0; rI < 4; ++rI) {
        int och = mt*16 + ksel*4 + rI;
        if (och < 27) {
            float v0 = acc0[rI] + ob[och];
            float v1 = acc1[rI] + ob[och];
            if (och >= 18) {
                v0 = 1.f / (1.f + __expf(-v0));   // mask sigmoid
                v1 = 1.f / (1.f + __expf(-v1));
            }
            int base = ((b*27 + och) << 14) + (y << 7) + gx0;
            om[base]      = v0;
            om[base + 16] = v1;
        }
    }
}

// ---------------- K2: deformable conv, HALF-ROW blocks (64 px, grid 1024).
// Amortizes param phase / barriers / ramp over 2x pixels (R21 k1 lesson).
// Phase A: 8-lane groups x uint4 taps, packed-f16; 6 items/group per third.
// Phase B: wave = 16 och x 4 px-tiles, sigma-permuted sl + ds_read_b128.
// LDS: params 1728 + sl[64][100] = 32,512 B -> 4 blocks/CU single pass.
__global__ __launch_bounds__(256) void k2_deform(
    const unsigned* __restrict__ f13t, const unsigned* __restrict__ wmf,
    const float* __restrict__ om, unsigned* __restrict__ alignedh,
    float* __restrict__ part)
{
    extern __shared__ unsigned lds[];
    unsigned* pl_a = lds;            // [9][64] addr|dx<<14|dy<<15
    unsigned* pl_w = lds + 576;      // [9][64] x uint2
    unsigned* sl   = lds + 1728;     // [64 px][100] permuted half2 samples

    int blk0 = blockIdx.x;
    int blk  = ((blk0 & 7) << 7) | (blk0 >> 3);   // bijective (1024 % 8 == 0)
    int xh = blk & 1;
    int y  = (blk >> 1) & 127;
    int b  = blk >> 8;

    int tid  = threadIdx.x;
    int lane = tid & 63;
    int wv   = tid >> 6;
    int row  = lane & 15;
    int ksel = lane >> 4;
    int cg   = tid & 7;          // phase-A channel group (4 pairs: 4cg..4cg+3)
    int grp  = tid >> 3;         // phase-A item group 0..31
    int pwb  = ((cg >> 2) << 4) | ((cg & 1) << 3) | (((cg >> 1) & 1) << 1);

    const float* omb = om + ((b*27) << 14) + (y << 7);
    const unsigned* ftb = f13t + (((size_t)b) << 20);

    // ---- param pre-phase: 576 items (k, px in half-row)
    for (int i = tid; i < 576; i += 256) {
        int k = i >> 6, lpx = i & 63;
        int gxp = xh*64 + lpx;
        float off0 = omb[((2*k)   << 14) + gxp];
        float off1 = omb[((2*k+1) << 14) + gxp];
        float mk   = omb[((18+k)  << 14) + gxp];   // sigmoided in K1

        float pyf = (float)y   + (float)(k/3) - 1.f + off0;
        float pxg = (float)gxp + (float)(k%3) - 1.f + off1;
        float fy = floorf(pyf), fx = floorf(pxg);
        int y0 = (int)fy, x0 = (int)fx;
        float wy = pyf - fy, wx = pxg - fx;
        float oy = 1.f - wy, ox = 1.f - wx;
        bool yv0 = (unsigned)y0     < (unsigned)HH;
        bool yv1 = (unsigned)(y0+1) < (unsigned)HH;
        bool xv0 = (unsigned)x0     < (unsigned)WW;
        bool xv1 = (unsigned)(x0+1) < (unsigned)WW;
        int y0c = min(max(y0, 0), 127);
        int x0c = min(max(x0, 0), 127);
        int dy = min(max(y0+1, 0), 127) - y0c;   // 0 or 1
        int dx = min(max(x0+1, 0), 127) - x0c;   // 0 or 1
        unsigned a = (unsigned)((y0c << 7) + x0c) | ((unsigned)dx << 14) | ((unsigned)dy << 15);
        float w00 = (yv0 && xv0) ? oy*ox*mk : 0.f;
        float w01 = (yv0 && xv1) ? oy*wx*mk : 0.f;
        float w10 = (yv1 && xv0) ? wy*ox*mk : 0.f;
        float w11 = (yv1 && xv1) ? wy*wx*mk : 0.f;
        pl_a[i] = a;
        pl_w[i*2]     = pk2u(w00, w01);
        pl_w[i*2 + 1] = pk2u(w10, w11);
    }
    __syncthreads();

    f32x4 accA = {0.f,0.f,0.f,0.f};   // px-tile 0 (px = row)
    f32x4 accB = {0.f,0.f,0.f,0.f};   // px-tile 1 (px = 16+row)
    f32x4 accC = {0.f,0.f,0.f,0.f};   // px-tile 2
    f32x4 accD = {0.f,0.f,0.f,0.f};   // px-tile 3

    const unsigned* wbase = wmf + (wv*64 + lane)*72;

#pragma unroll 1
    for (int th = 0; th < 3; ++th) {
        uint4 wq[6];
#pragma unroll
        for (int m = 0; m < 6; ++m)
            wq[m] = *(const uint4*)&wbase[th*24 + m*4];

        // phase A: 192 items (ktl,px); 8-lane group = one item, 6/group
#pragma unroll 3
        for (int it = 0; it < 6; ++it) {
            int item = it*32 + grp;            // 0..191
            int ktl  = item >> 6;              // 0..2
            int px   = item & 63;
            int k    = th*3 + ktl;
            int pidx = k*64 + px;
            unsigned a = pl_a[pidx];
            uint2 wpk = *(const uint2*)&pl_w[pidx*2];
            int i00 = (int)(a & 0x3FFFu);
            int dx  = (int)((a >> 14) & 1u);
            int i10 = i00 + (((int)(a >> 15) & 1) << 7);
            h2 hw01 = u2h(wpk.x);
            h2 hw23 = u2h(wpk.y);
            h2 w00d = {hw01.x, hw01.x}, w01d = {hw01.y, hw01.y};
            h2 w10d = {hw23.x, hw23.x}, w11d = {hw23.y, hw23.y};

            uint4 t00 = *(const uint4*)&ftb[(size_t)(i00     )*64 + 4*cg];
            uint4 t01 = *(const uint4*)&ftb[(size_t)(i00 + dx)*64 + 4*cg];
            uint4 t10 = *(const uint4*)&ftb[(size_t)(i10     )*64 + 4*cg];
            uint4 t11 = *(const uint4*)&ftb[(size_t)(i10 + dx)*64 + 4*cg];

            h2 v0 = u2h(t00.x)*w00d + u2h(t01.x)*w01d + u2h(t10.x)*w10d + u2h(t11.x)*w11d;
            h2 v1 = u2h(t00.y)*w00d + u2h(t01.y)*w01d + u2h(t10.y)*w10d + u2h(t11.y)*w11d;
            h2 v2 = u2h(t00.z)*w00d + u2h(t01.z)*w01d + u2h(t10.z)*w10d + u2h(t11.z)*w11d;
            h2 v3 = u2h(t00.w)*w00d + u2h(t01.w)*w01d + u2h(t10.w)*w10d + u2h(t11.w)*w11d;

            int bs = px*100 + ktl*32 + pwb;
            *(uint2*)&sl[bs]     = make_uint2(h2u(v0), h2u(v1));
            *(uint2*)&sl[bs + 4] = make_uint2(h2u(v2), h2u(v3));
        }
        __syncthreads();

        // phase B: 6 double-K-blocks x 4 px-tiles, ds_read_b128
        const unsigned* bpA = &sl[(row     )*100 + ksel*4];
        const unsigned* bpB = &sl[(16+row  )*100 + ksel*4];
        const unsigned* bpC = &sl[(32+row  )*100 + ksel*4];
        const unsigned* bpD = &sl[(48+row  )*100 + ksel*4];
#pragma unroll
        for (int m = 0; m < 6; ++m) {
            uint4 bvA = *(const uint4*)&bpA[m*16];
            uint4 bvB = *(const uint4*)&bpB[m*16];
            uint4 bvC = *(const uint4*)&bpC[m*16];
            uint4 bvD = *(const uint4*)&bpD[m*16];
            U2H waA, waB, sa, sb;
            waA.u.x = wq[m].x; waA.u.y = wq[m].y;
            waB.u.x = wq[m].z; waB.u.y = wq[m].w;
            sa.u.x = bvA.x; sa.u.y = bvA.y;
            sb.u.x = bvA.z; sb.u.y = bvA.w;
            accA = __builtin_amdgcn_mfma_f32_16x16x16f16(waA.h, sa.h, accA, 0, 0, 0);
            accA = __builtin_amdgcn_mfma_f32_16x16x16f16(waB.h, sb.h, accA, 0, 0, 0);
            sa.u.x = bvB.x; sa.u.y = bvB.y;
            sb.u.x = bvB.z; sb.u.y = bvB.w;
            accB = __builtin_amdgcn_mfma_f32_16x16x16f16(waA.h, sa.h, accB, 0, 0, 0);
            accB = __builtin_amdgcn_mfma_f32_16x16x16f16(waB.h, sb.h, accB, 0, 0, 0);
            sa.u.x = bvC.x; sa.u.y = bvC.y;
            sb.u.x = bvC.z; sb.u.y = bvC.w;
            accC = __builtin_amdgcn_mfma_f32_16x16x16f16(waA.h, sa.h, accC, 0, 0, 0);
            accC = __builtin_amdgcn_mfma_f32_16x16x16f16(waB.h, sb.h, accC, 0, 0, 0);
            sa.u.x = bvD.x; sa.u.y = bvD.y;
            sb.u.x = bvD.z; sb.u.y = bvD.w;
            accD = __builtin_amdgcn_mfma_f32_16x16x16f16(waA.h, sa.h, accD, 0, 0, 0);
            accD = __builtin_amdgcn_mfma_f32_16x16x16f16(waB.h, sb.h, accD, 0, 0, 0);
        }
        __syncthreads();
    }

    // write aligned (packed f16 pairs) + per-block stats partials
    float* sred = (float*)lds;   // reuse (safe: past last barrier)
#pragma unroll
    for (int rI = 0; rI < 4; ++rI) {
        int och = wv*16 + ksel*4 + rI;
        float v0 = accA[rI], v1 = accB[rI], v2 = accC[rI], v3 = accD[rI];
        int ai = (((b*CC + och) << 13)) + (y << 6) + row;
        alignedh[ai + ((2*xh    ) << 4)] = pk2u(v0, v1);
        alignedh[ai + ((2*xh + 1) << 4)] = pk2u(v2, v3);
        float s  = v0 + v1 + v2 + v3;
        float sq = v0*v0 + v1*v1 + v2*v2 + v3*v3;
#pragma unroll
        for (int off = 1; off < 16; off <<= 1) {
            s  += __shfl_xor(s,  off, 64);
            sq += __shfl_xor(sq, off, 64);
        }
        if (row == 0) { sred[och] = s; sred[64 + och] = sq; }
    }
    __syncthreads();
    for (int i = tid; i < 128; i += 256)
        part[(size_t)blk*128 + i] = sred[i];
}

// ---------------- K3b: reduce 1024 per-block partials -> stats[128]
__global__ __launch_bounds__(256) void k3b_reduce(
    const float* __restrict__ part, float* __restrict__ stats)
{
    int i = blockIdx.x;           // 0..127
    int tid = threadIdx.x;
    float s = 0.f;
    for (int j = tid; j < 1024; j += 256) s += part[(size_t)j*128 + i];
    for (int off = 32; off > 0; off >>= 1) s += __shfl_down(s, off, 64);
    __shared__ float rs[4];
    int w = tid >> 6;
    if ((tid & 63) == 0) rs[w] = s;
    __syncthreads();
    if (tid == 0) stats[i] = rs[0] + rs[1] + rs[2] + rs[3];
}

// ---------------- K4: normalize + affine, f16-packed input -> f32 out.
__global__ __launch_bounds__(256) void k4_norm(
    const unsigned* __restrict__ alignedh, const float* __restrict__ stats,
    const float* __restrict__ gamma, const float* __restrict__ beta,
    float* __restrict__ out)
{
    const float invN = 1.f / 65536.f;
    int i4 = blockIdx.x*256 + threadIdx.x;     // 0..524287
    int u  = i4 << 2;
    int c  = (u >> 13) & 63;
    int lx = u & 15;
    int xq = (u >> 4) & 3;
    int y  = (u >> 6) & 127;
    int bc = u >> 13;                          // b*64 + c

    float mean = stats[c] * invN;
    float var  = stats[64 + c] * invN - mean*mean;
    float sc = gamma[c] * rsqrtf(var + 1e-5f);
    float sh = beta[c] - mean*sc;

    uint4 v = *(const uint4*)&alignedh[u];
    h2 p0 = u2h(v.x), p1 = u2h(v.y), p2 = u2h(v.z), p3 = u2h(v.w);
    float4 lo = make_float4((float)p0.x*sc + sh, (float)p1.x*sc + sh,
                            (float)p2.x*sc + sh, (float)p3.x*sc + sh);
    float4 hi = make_float4((float)p0.y*sc + sh, (float)p1.y*sc + sh,
                            (float)p2.y*sc + sh, (float)p3.y*sc + sh);
    int ob = (bc << 14) + (y << 7) + xq*32 + lx;
    *(float4*)&out[ob]      = lo;
    *(float4*)&out[ob + 16] = hi;
}

extern "C" void kernel_launch(void* const* d_in, const int* in_sizes, int n_in,
                              void* d_out, int out_size, void* d_ws, size_t ws_size,
                              hipStream_t stream)
{
    const float* f1    = (const float*)d_in[0];
    const float* f3    = (const float*)d_in[1];
    const float* ow    = (const float*)d_in[2];
    const float* ob    = (const float*)d_in[3];
    const float* mw    = (const float*)d_in[4];
    const float* gamma = (const float*)d_in[5];
    const float* beta  = (const float*)d_in[6];
    float* out = (float*)d_out;

    float* om     = (float*)d_ws;                 // [4][27][128][128] = 7,077,888 B
    float* stats  = om + 4*27*HWP;                // [128] floats (512 reserved)
    unsigned* wmf = (unsigned*)(stats + 512);     // 18432 u32
    unsigned* wof = wmf + 18432;                  // 18432 u32
    unsigned* f13t = wof + 18432;                 // [4][128][128][64] u32 = 16 MB
    float* part   = (float*)(f13t + 4*HWP*64);    // [1024][128] floats
    unsigned* alignedh = (unsigned*)(part + 2048*128);  // [4][64][128][64] u32 = 33.5 MB

    const int lds1 = 4*2312*4;                    // 36,992 B (k1)
    const int lds2 = (1728 + 64*100) * 4;         // 32,512 B (k2)
    (void)hipFuncSetAttribute((const void*)k1_offset_conv,
        hipFuncAttributeMaxDynamicSharedMemorySize, lds1);
    (void)hipFuncSetAttribute((const void*)k2_deform,
        hipFuncAttributeMaxDynamicSharedMemorySize, lds2);

    hipLaunchKernelGGL(kTm, dim3(656), dim3(256), 0, stream,
                       f1, f3, ow, mw, f13t, wmf, wof);
    hipLaunchKernelGGL(k1_offset_conv, dim3(1024), dim3(256), lds1, stream,
                       f13t, wof, ob, om);
    hipLaunchKernelGGL(k2_deform, dim3(1024), dim3(256), lds2, stream,
                       f13t, wmf, om, alignedh, part);
    hipLaunchKernelGGL(k3b_reduce, dim3(128), dim3(256), 0, stream, part, stats);
    hipLaunchKernelGGL(k4_norm, dim3(2048), dim3(256), 0, stream,
                       alignedh, stats, gamma, beta, out);
}